// Round 1
// baseline (15716.745 us; speedup 1.0000x reference)
//
#include <hip/hip_runtime.h>
#include <hip/hip_bf16.h>
#include <math.h>

#define N_NODES 883
#define T_STEPS 12
#define BATCH 64
#define DE 10
#define KI 132          // CHEB_K * (DIN + DOUT) = 2 * 66
#define NCOLS 8192      // 2 dirs * 64 batch * 64 hidden
#define XCOLS 1536      // T * B * DIN

// ---------------------------------------------------------------------------
// S = softmax(relu(E E^T), axis=1) + adj     (one block per row n)
// ---------------------------------------------------------------------------
__global__ __launch_bounds__(256) void k_computeS(const float* __restrict__ E,
                                                  const float* __restrict__ adj,
                                                  float* __restrict__ S) {
    int n = blockIdx.x;
    int tid = threadIdx.x;
    __shared__ float l[N_NODES];
    __shared__ float red[8];
    float En[DE];
#pragma unroll
    for (int d = 0; d < DE; ++d) En[d] = E[n * DE + d];

    float lmax = -1e30f;
    for (int m = tid; m < N_NODES; m += 256) {
        float dot = 0.f;
#pragma unroll
        for (int d = 0; d < DE; ++d) dot += En[d] * E[m * DE + d];
        dot = fmaxf(dot, 0.f);
        l[m] = dot;
        lmax = fmaxf(lmax, dot);
    }
    int wave = tid >> 6, lane = tid & 63;
    for (int off = 32; off > 0; off >>= 1) lmax = fmaxf(lmax, __shfl_down(lmax, off));
    if (lane == 0) red[wave] = lmax;
    __syncthreads();
    float gmax = fmaxf(fmaxf(red[0], red[1]), fmaxf(red[2], red[3]));
    __syncthreads();

    float lsum = 0.f;
    for (int m = tid; m < N_NODES; m += 256) {
        float e = expf(l[m] - gmax);
        l[m] = e;
        lsum += e;
    }
    for (int off = 32; off > 0; off >>= 1) lsum += __shfl_down(lsum, off);
    if (lane == 0) red[wave] = lsum;
    __syncthreads();
    float inv = 1.0f / (red[0] + red[1] + red[2] + red[3]);
    for (int m = tid; m < N_NODES; m += 256) {
        S[(size_t)n * N_NODES + m] = l[m] * inv + adj[(size_t)n * N_NODES + m];
    }
}

// ---------------------------------------------------------------------------
// XT[m][(t*64+b)*2+i] = x[b,t,m,i]
// ---------------------------------------------------------------------------
__global__ void k_transposeX(const float* __restrict__ x, float* __restrict__ XT) {
    int idx = blockIdx.x * blockDim.x + threadIdx.x;
    const int total = N_NODES * XCOLS;
    if (idx >= total) return;
    int c = idx % XCOLS;
    int m = idx / XCOLS;
    int t = c >> 7;
    int b = (c >> 1) & 63;
    int i = c & 1;
    XT[idx] = x[(((size_t)b * T_STEPS + t) * N_NODES + m) * 2 + i];
}

// ---------------------------------------------------------------------------
// C[M x NC] = A[M x K] * B[K x NC];  M = K = 883.  128x128 tile, 8x8 micro.
// ---------------------------------------------------------------------------
#define BM 128
#define BN 128
#define BK 16

__global__ __launch_bounds__(256) void k_gemm(const float* __restrict__ A,
                                              const float* __restrict__ B,
                                              float* __restrict__ C, int NC) {
    const int M = N_NODES, K = N_NODES;
    __shared__ float As[BK][BM + 4];   // [16][132]
    __shared__ float Bs[BK][BN];       // [16][128]
    int tid = threadIdx.x;
    int row0 = blockIdx.y * BM;
    int col0 = blockIdx.x * BN;
    int tx = tid & 15, ty = tid >> 4;
    float acc[8][8] = {};
    int la_r = (tid * 8) >> 4;     // row within tile
    int la_k = (tid * 8) & 15;     // k start (0 or 8)
    int lb_k = (tid * 8) >> 7;     // k row
    int lb_c = (tid * 8) & 127;    // col start
    const int nk = (K + BK - 1) / BK;
    for (int kt = 0; kt < nk; ++kt) {
        int k0 = kt * BK;
        int ar = row0 + la_r;
#pragma unroll
        for (int j = 0; j < 8; ++j) {
            int k = k0 + la_k + j;
            As[la_k + j][la_r] = (ar < M && k < K) ? A[(size_t)ar * K + k] : 0.f;
        }
        int bk = k0 + lb_k;
        const float* brow = B + (size_t)bk * NC + col0 + lb_c;
#pragma unroll
        for (int j = 0; j < 8; ++j) {
            Bs[lb_k][lb_c + j] = (bk < K) ? brow[j] : 0.f;
        }
        __syncthreads();
#pragma unroll
        for (int kk = 0; kk < BK; ++kk) {
            float a[8], b[8];
#pragma unroll
            for (int i = 0; i < 8; ++i) a[i] = As[kk][ty * 8 + i];
#pragma unroll
            for (int j = 0; j < 8; ++j) b[j] = Bs[kk][tx * 8 + j];
#pragma unroll
            for (int i = 0; i < 8; ++i)
#pragma unroll
                for (int j = 0; j < 8; ++j) acc[i][j] += a[i] * b[j];
        }
        __syncthreads();
    }
#pragma unroll
    for (int i = 0; i < 8; ++i) {
        int r = row0 + ty * 8 + i;
        if (r < M) {
            float* crow = C + (size_t)r * NC + col0 + tx * 8;
#pragma unroll
            for (int j = 0; j < 8; ++j) crow[j] = acc[i][j];
        }
    }
}

// ---------------------------------------------------------------------------
// Gate apply: zr = sigmoid(sum_ki inp[ki,b] * Wn[ki,o] + bn[o])
//   inp k=0: concat(x_t, h);  k=1: concat(Sx_t, S h)
// Emits Z[dir,n,b,j] and RH[n][dir*4096 + b*64 + j] = r * h
// 128 threads: o = tid, each accumulates all 64 b.
// ---------------------------------------------------------------------------
__global__ __launch_bounds__(128) void k_apply_gate(
    const float* __restrict__ x, const float* __restrict__ E,
    const float* __restrict__ Wg_f, const float* __restrict__ bg_f,
    const float* __restrict__ Wg_b, const float* __restrict__ bg_b,
    const float* __restrict__ SX, const float* __restrict__ SH,
    const float* __restrict__ H, float* __restrict__ RH,
    float* __restrict__ Z, int t) {
    int n = blockIdx.x, dir = blockIdx.y;
    int tid = threadIdx.x;
    int tt = dir ? (T_STEPS - 1 - t) : t;
    const float* Wg = dir ? Wg_b : Wg_f;
    const float* bg = dir ? bg_b : bg_f;
    __shared__ float inp[KI][68];

    {
        int b = tid >> 1, i = tid & 1;
        inp[i][b] = x[(((size_t)b * T_STEPS + tt) * N_NODES + n) * 2 + i];
        inp[66 + i][b] = SX[(size_t)n * XCOLS + tt * 128 + tid];
    }
    const float* hrow = H + (size_t)n * NCOLS + dir * 4096;
    const float* shrow = SH + (size_t)n * NCOLS + dir * 4096;
    for (int idx = tid; idx < 4096; idx += 128) {
        int b = idx >> 6, j = idx & 63;
        inp[2 + j][b] = hrow[idx];
        inp[66 + 2 + j][b] = shrow[idx];
    }
    float Ed[DE];
#pragma unroll
    for (int d = 0; d < DE; ++d) Ed[d] = E[n * DE + d];
    int o = tid;
    float bias = 0.f;
#pragma unroll
    for (int d = 0; d < DE; ++d) bias += Ed[d] * bg[d * 128 + o];
    float acc[64];
#pragma unroll
    for (int b = 0; b < 64; ++b) acc[b] = bias;
    __syncthreads();

    const float* wbase = Wg + o;
    for (int ki = 0; ki < KI; ++ki) {
        float w = 0.f;
#pragma unroll
        for (int d = 0; d < DE; ++d) w += Ed[d] * wbase[(size_t)(d * KI + ki) * 128];
        const float* row = &inp[ki][0];
#pragma unroll
        for (int bq = 0; bq < 16; ++bq) {
            float4 v = *(const float4*)&row[bq * 4];
            acc[bq * 4 + 0] += v.x * w;
            acc[bq * 4 + 1] += v.y * w;
            acc[bq * 4 + 2] += v.z * w;
            acc[bq * 4 + 3] += v.w * w;
        }
    }

    if (o < 64) {
        float* zrow = Z + ((size_t)(dir * N_NODES + n)) * 4096;
#pragma unroll
        for (int b = 0; b < 64; ++b) {
            float zv = 1.f / (1.f + expf(-acc[b]));
            zrow[b * 64 + o] = zv;
        }
    } else {
        int j = o - 64;
        float* rhrow = RH + (size_t)n * NCOLS + dir * 4096;
#pragma unroll
        for (int b = 0; b < 64; ++b) {
            float rv = 1.f / (1.f + expf(-acc[b]));
            rhrow[b * 64 + j] = rv * inp[2 + j][b];
        }
    }
}

// ---------------------------------------------------------------------------
// Candidate apply: hc = tanh(...); h_new = z*h + (1-z)*hc; writes H and out.
// 128 threads: o = tid&63, bh = tid>>6 handles 32 b.
// ---------------------------------------------------------------------------
__global__ __launch_bounds__(128) void k_apply_cand(
    const float* __restrict__ x, const float* __restrict__ E,
    const float* __restrict__ Wc_f, const float* __restrict__ bc_f,
    const float* __restrict__ Wc_b, const float* __restrict__ bc_b,
    const float* __restrict__ SX, const float* __restrict__ SRH,
    const float* __restrict__ RH, const float* __restrict__ Z,
    float* __restrict__ H, float* __restrict__ out, int t) {
    int n = blockIdx.x, dir = blockIdx.y;
    int tid = threadIdx.x;
    int tt = dir ? (T_STEPS - 1 - t) : t;
    const float* Wc = dir ? Wc_b : Wc_f;
    const float* bc = dir ? bc_b : bc_f;
    __shared__ float inp[KI][68];

    {
        int b = tid >> 1, i = tid & 1;
        inp[i][b] = x[(((size_t)b * T_STEPS + tt) * N_NODES + n) * 2 + i];
        inp[66 + i][b] = SX[(size_t)n * XCOLS + tt * 128 + tid];
    }
    const float* rhrow = RH + (size_t)n * NCOLS + dir * 4096;
    const float* srhrow = SRH + (size_t)n * NCOLS + dir * 4096;
    for (int idx = tid; idx < 4096; idx += 128) {
        int b = idx >> 6, j = idx & 63;
        inp[2 + j][b] = rhrow[idx];
        inp[66 + 2 + j][b] = srhrow[idx];
    }
    float Ed[DE];
#pragma unroll
    for (int d = 0; d < DE; ++d) Ed[d] = E[n * DE + d];
    int o = tid & 63, bh = tid >> 6;
    float bias = 0.f;
#pragma unroll
    for (int d = 0; d < DE; ++d) bias += Ed[d] * bc[d * 64 + o];
    float acc[32];
#pragma unroll
    for (int bb = 0; bb < 32; ++bb) acc[bb] = bias;
    __syncthreads();

    const float* wbase = Wc + o;
    for (int ki = 0; ki < KI; ++ki) {
        float w = 0.f;
#pragma unroll
        for (int d = 0; d < DE; ++d) w += Ed[d] * wbase[(size_t)(d * KI + ki) * 64];
        const float* row = &inp[ki][bh * 32];
#pragma unroll
        for (int bq = 0; bq < 8; ++bq) {
            float4 v = *(const float4*)&row[bq * 4];
            acc[bq * 4 + 0] += v.x * w;
            acc[bq * 4 + 1] += v.y * w;
            acc[bq * 4 + 2] += v.z * w;
            acc[bq * 4 + 3] += v.w * w;
        }
    }

    float* hrow = H + (size_t)n * NCOLS + dir * 4096;
    const float* zrow = Z + ((size_t)(dir * N_NODES + n)) * 4096;
#pragma unroll
    for (int bb = 0; bb < 32; ++bb) {
        int b = bh * 32 + bb;
        float hc = tanhf(acc[bb]);
        float hp = hrow[b * 64 + o];
        float zv = zrow[b * 64 + o];
        float hn = zv * hp + (1.f - zv) * hc;
        hrow[b * 64 + o] = hn;
        out[(((size_t)b * T_STEPS + t) * N_NODES + n) * 128 + dir * 64 + o] = hn;
    }
}

// ---------------------------------------------------------------------------
extern "C" void kernel_launch(void* const* d_in, const int* in_sizes, int n_in,
                              void* d_out, int out_size, void* d_ws, size_t ws_size,
                              hipStream_t stream) {
    const float* x    = (const float*)d_in[0];
    const float* adj  = (const float*)d_in[1];
    const float* E    = (const float*)d_in[2];
    const float* Wg_f = (const float*)d_in[3];
    const float* bg_f = (const float*)d_in[4];
    const float* Wc_f = (const float*)d_in[5];
    const float* bc_f = (const float*)d_in[6];
    const float* Wg_b = (const float*)d_in[7];
    const float* bg_b = (const float*)d_in[8];
    const float* Wc_b = (const float*)d_in[9];
    const float* bc_b = (const float*)d_in[10];
    float* out = (float*)d_out;
    float* ws  = (float*)d_ws;

    size_t off = 0;
    auto alloc = [&](size_t nelem) {
        float* p = ws + off;
        off += (nelem + 255) & ~(size_t)255;
        return p;
    };
    float* S  = alloc((size_t)N_NODES * N_NODES);
    float* XT = alloc((size_t)N_NODES * XCOLS);
    float* SX = alloc((size_t)N_NODES * XCOLS);
    float* H  = alloc((size_t)N_NODES * NCOLS);
    float* SH = alloc((size_t)N_NODES * NCOLS);
    float* RH = alloc((size_t)N_NODES * NCOLS);
    float* Z  = alloc((size_t)N_NODES * NCOLS);

    hipMemsetAsync(H, 0, (size_t)N_NODES * NCOLS * sizeof(float), stream);

    k_computeS<<<N_NODES, 256, 0, stream>>>(E, adj, S);

    {
        int total = N_NODES * XCOLS;
        k_transposeX<<<(total + 255) / 256, 256, 0, stream>>>(x, XT);
    }
    {
        dim3 g(XCOLS / BN, (N_NODES + BM - 1) / BM);  // 12 x 7
        k_gemm<<<g, 256, 0, stream>>>(S, XT, SX, XCOLS);
    }

    dim3 gmain(NCOLS / BN, (N_NODES + BM - 1) / BM);  // 64 x 7
    dim3 gapply(N_NODES, 2);
    for (int t = 0; t < T_STEPS; ++t) {
        k_gemm<<<gmain, 256, 0, stream>>>(S, H, SH, NCOLS);
        k_apply_gate<<<gapply, 128, 0, stream>>>(x, E, Wg_f, bg_f, Wg_b, bg_b,
                                                 SX, SH, H, RH, Z, t);
        k_gemm<<<gmain, 256, 0, stream>>>(S, RH, SH, NCOLS);
        k_apply_cand<<<gapply, 128, 0, stream>>>(x, E, Wc_f, bc_f, Wc_b, bc_b,
                                                 SX, SH, RH, Z, H, out, t);
    }
}

// Round 3
// 5246.166 us; speedup vs baseline: 2.9959x; 2.9959x over previous
//
#include <hip/hip_runtime.h>
#include <math.h>

#define N_NODES 883
#define KPAD 896
#define T_STEPS 12
#define DE 10
#define KI 132          // CHEB_K * (DIN + DOUT) = 2 * 66
#define NCOLS 8192      // 2 dirs * 64 batch * 64 hidden
#define XCOLS 1536      // T * B * DIN

typedef _Float16 f16;
typedef __attribute__((ext_vector_type(8))) _Float16 f16x8;
typedef __attribute__((ext_vector_type(4))) float f32x4;

__device__ inline void gload16(const void* g, void* l) {
    __builtin_amdgcn_global_load_lds(
        (const __attribute__((address_space(1))) unsigned int*)g,
        (__attribute__((address_space(3))) unsigned int*)l, 16, 0, 0);
}

// ---------------------------------------------------------------------------
// Sh[n][m] (fp16, padded to 896x896) = softmax(relu(E E^T), axis=1) + adj
// ---------------------------------------------------------------------------
__global__ __launch_bounds__(256) void k_computeS(const float* __restrict__ E,
                                                  const float* __restrict__ adj,
                                                  f16* __restrict__ Sh) {
    int n = blockIdx.x;
    int tid = threadIdx.x;
    __shared__ float l[N_NODES];
    __shared__ float red[8];
    float En[DE];
#pragma unroll
    for (int d = 0; d < DE; ++d) En[d] = E[n * DE + d];

    float lmax = -1e30f;
    for (int m = tid; m < N_NODES; m += 256) {
        float dot = 0.f;
#pragma unroll
        for (int d = 0; d < DE; ++d) dot += En[d] * E[m * DE + d];
        dot = fmaxf(dot, 0.f);
        l[m] = dot;
        lmax = fmaxf(lmax, dot);
    }
    int wave = tid >> 6, lane = tid & 63;
    for (int off = 32; off > 0; off >>= 1) lmax = fmaxf(lmax, __shfl_down(lmax, off));
    if (lane == 0) red[wave] = lmax;
    __syncthreads();
    float gmax = fmaxf(fmaxf(red[0], red[1]), fmaxf(red[2], red[3]));
    __syncthreads();

    float lsum = 0.f;
    for (int m = tid; m < N_NODES; m += 256) {
        float e = expf(l[m] - gmax);
        l[m] = e;
        lsum += e;
    }
    for (int off = 32; off > 0; off >>= 1) lsum += __shfl_down(lsum, off);
    if (lane == 0) red[wave] = lsum;
    __syncthreads();
    float inv = 1.0f / (red[0] + red[1] + red[2] + red[3]);
    for (int m = tid; m < N_NODES; m += 256) {
        Sh[(size_t)n * KPAD + m] = (f16)(l[m] * inv + adj[(size_t)n * N_NODES + m]);
    }
}

// ---------------------------------------------------------------------------
// XTt[c][m] (fp16, [1536][896]) = x[b,t,m,i] with c=(t*64+b)*2+i
// ---------------------------------------------------------------------------
__global__ void k_buildXT(const float* __restrict__ x, f16* __restrict__ XTt) {
    int idx = blockIdx.x * blockDim.x + threadIdx.x;
    if (idx >= XCOLS * N_NODES) return;
    int m = idx % N_NODES;
    int c = idx / N_NODES;
    int t = c >> 7;
    int b = (c >> 1) & 63;
    int i = c & 1;
    XTt[(size_t)c * KPAD + m] = (f16)x[(((size_t)b * T_STEPS + t) * N_NODES + m) * 2 + i];
}

// ---------------------------------------------------------------------------
// C[r][c] (fp32, r<883) = sum_k A[r][k] * Bt[c][k]
// A: [KPAD][KPAD] fp16 (S, zero-padded). Bt: [NC][KPAD] fp16 (zero-padded).
// 128x128 tile, 4 waves (each 64x64), BK=32, mfma 16x16x32 f16.
// ---------------------------------------------------------------------------
__global__ __launch_bounds__(256) void k_gemm_f16(const f16* __restrict__ A,
                                                  const f16* __restrict__ Bt,
                                                  float* __restrict__ C, int NC) {
    __shared__ f16 Als[128 * 32];
    __shared__ f16 Bls[128 * 32];
    int tid = threadIdx.x;
    int w = tid >> 6, l = tid & 63;
    int wr = w >> 1, wc = w & 1;
    int row0 = blockIdx.y * 128;
    int col0 = blockIdx.x * 128;
    int rr = l >> 2;           // staging: row within 16-row chunk
    int cc = (l & 3) * 8;      // staging: k offset (elements)
    int lr = l & 15, lg = l >> 4;

    const f16* a0 = A + (size_t)(row0 + w * 32 + rr) * KPAD + cc;
    const f16* a1 = a0 + (size_t)16 * KPAD;
    const f16* b0 = Bt + (size_t)(col0 + w * 32 + rr) * KPAD + cc;
    const f16* b1 = b0 + (size_t)16 * KPAD;
    f16* la0 = &Als[(w * 32) * 32];
    f16* la1 = &Als[(w * 32 + 16) * 32];
    f16* lb0 = &Bls[(w * 32) * 32];
    f16* lb1 = &Bls[(w * 32 + 16) * 32];

    f32x4 acc[4][4];
#pragma unroll
    for (int m = 0; m < 4; ++m)
#pragma unroll
        for (int n = 0; n < 4; ++n) acc[m][n] = (f32x4)(0.f);

    for (int kt = 0; kt < KPAD / 32; ++kt) {
        int k0 = kt * 32;
        gload16(a0 + k0, la0);
        gload16(a1 + k0, la1);
        gload16(b0 + k0, lb0);
        gload16(b1 + k0, lb1);
        __syncthreads();
        f16x8 af[4], bf[4];
#pragma unroll
        for (int m = 0; m < 4; ++m)
            af[m] = *(const f16x8*)&Als[(wr * 64 + m * 16 + lr) * 32 + lg * 8];
#pragma unroll
        for (int n = 0; n < 4; ++n)
            bf[n] = *(const f16x8*)&Bls[(wc * 64 + n * 16 + lr) * 32 + lg * 8];
#pragma unroll
        for (int m = 0; m < 4; ++m)
#pragma unroll
            for (int n = 0; n < 4; ++n)
                acc[m][n] = __builtin_amdgcn_mfma_f32_16x16x32_f16(af[m], bf[n], acc[m][n], 0, 0, 0);
        __syncthreads();
    }

#pragma unroll
    for (int m = 0; m < 4; ++m) {
        int gr0 = row0 + wr * 64 + m * 16 + lg * 4;
#pragma unroll
        for (int n = 0; n < 4; ++n) {
            int gc = col0 + wc * 64 + n * 16 + lr;
            f32x4 v = acc[m][n];
#pragma unroll
            for (int q = 0; q < 4; ++q) {
                int r = gr0 + q;
                if (r < N_NODES) C[(size_t)r * NC + gc] = v[q];
            }
        }
    }
}

// ---------------------------------------------------------------------------
// Gate apply. Reads SX/SH (fp32), H/x (fp32). Writes Z (fp32),
// RH (fp32 row-major) and RHBt (fp16 transposed [NCOLS][KPAD]).
// ---------------------------------------------------------------------------
__global__ __launch_bounds__(128) void k_apply_gate(
    const float* __restrict__ x, const float* __restrict__ E,
    const float* __restrict__ Wg_f, const float* __restrict__ bg_f,
    const float* __restrict__ Wg_b, const float* __restrict__ bg_b,
    const float* __restrict__ SX, const float* __restrict__ SH,
    const float* __restrict__ H, float* __restrict__ RH,
    f16* __restrict__ RHBt, float* __restrict__ Z, int t) {
    int n = blockIdx.x, dir = blockIdx.y;
    int tid = threadIdx.x;
    int tt = dir ? (T_STEPS - 1 - t) : t;
    const float* Wg = dir ? Wg_b : Wg_f;
    const float* bg = dir ? bg_b : bg_f;
    __shared__ float inp[KI][68];

    {
        int b = tid >> 1, i = tid & 1;
        inp[i][b] = x[(((size_t)b * T_STEPS + tt) * N_NODES + n) * 2 + i];
        inp[66 + i][b] = SX[(size_t)n * XCOLS + tt * 128 + tid];
    }
    const float* hrow = H + (size_t)n * NCOLS + dir * 4096;
    const float* shrow = SH + (size_t)n * NCOLS + dir * 4096;
    for (int idx = tid; idx < 4096; idx += 128) {
        int b = idx >> 6, j = idx & 63;
        inp[2 + j][b] = hrow[idx];
        inp[66 + 2 + j][b] = shrow[idx];
    }
    float Ed[DE];
#pragma unroll
    for (int d = 0; d < DE; ++d) Ed[d] = E[n * DE + d];
    int o = tid;
    float bias = 0.f;
#pragma unroll
    for (int d = 0; d < DE; ++d) bias += Ed[d] * bg[d * 128 + o];
    float acc[64];
#pragma unroll
    for (int b = 0; b < 64; ++b) acc[b] = bias;
    __syncthreads();

    const float* wbase = Wg + o;
    for (int ki = 0; ki < KI; ++ki) {
        float w = 0.f;
#pragma unroll
        for (int d = 0; d < DE; ++d) w += Ed[d] * wbase[(size_t)(d * KI + ki) * 128];
        const float* row = &inp[ki][0];
#pragma unroll
        for (int bq = 0; bq < 16; ++bq) {
            float4 v = *(const float4*)&row[bq * 4];
            acc[bq * 4 + 0] += v.x * w;
            acc[bq * 4 + 1] += v.y * w;
            acc[bq * 4 + 2] += v.z * w;
            acc[bq * 4 + 3] += v.w * w;
        }
    }

    if (o < 64) {
        float* zrow = Z + ((size_t)(dir * N_NODES + n)) * 4096;
#pragma unroll
        for (int b = 0; b < 64; ++b) {
            zrow[b * 64 + o] = 1.f / (1.f + expf(-acc[b]));
        }
    } else {
        int j = o - 64;
        float* rhrow = RH + (size_t)n * NCOLS + dir * 4096;
#pragma unroll
        for (int b = 0; b < 64; ++b) {
            float rv = 1.f / (1.f + expf(-acc[b]));
            float rhv = rv * inp[2 + j][b];
            rhrow[b * 64 + j] = rhv;
            RHBt[(size_t)(dir * 4096 + b * 64 + j) * KPAD + n] = (f16)rhv;
        }
    }
}

// ---------------------------------------------------------------------------
// Candidate apply. Reads SX/SRH/Z (fp32), RH/H/x (fp32).
// Writes H (fp32), HBt (fp16 transposed), out (fp32).
// ---------------------------------------------------------------------------
__global__ __launch_bounds__(128) void k_apply_cand(
    const float* __restrict__ x, const float* __restrict__ E,
    const float* __restrict__ Wc_f, const float* __restrict__ bc_f,
    const float* __restrict__ Wc_b, const float* __restrict__ bc_b,
    const float* __restrict__ SX, const float* __restrict__ SRH,
    const float* __restrict__ RH, const float* __restrict__ Z,
    float* __restrict__ H, f16* __restrict__ HBt,
    float* __restrict__ out, int t) {
    int n = blockIdx.x, dir = blockIdx.y;
    int tid = threadIdx.x;
    int tt = dir ? (T_STEPS - 1 - t) : t;
    const float* Wc = dir ? Wc_b : Wc_f;
    const float* bc = dir ? bc_b : bc_f;
    __shared__ float inp[KI][68];

    {
        int b = tid >> 1, i = tid & 1;
        inp[i][b] = x[(((size_t)b * T_STEPS + tt) * N_NODES + n) * 2 + i];
        inp[66 + i][b] = SX[(size_t)n * XCOLS + tt * 128 + tid];
    }
    const float* rhrow = RH + (size_t)n * NCOLS + dir * 4096;
    const float* srhrow = SRH + (size_t)n * NCOLS + dir * 4096;
    for (int idx = tid; idx < 4096; idx += 128) {
        int b = idx >> 6, j = idx & 63;
        inp[2 + j][b] = rhrow[idx];
        inp[66 + 2 + j][b] = srhrow[idx];
    }
    float Ed[DE];
#pragma unroll
    for (int d = 0; d < DE; ++d) Ed[d] = E[n * DE + d];
    int o = tid & 63, bh = tid >> 6;
    float bias = 0.f;
#pragma unroll
    for (int d = 0; d < DE; ++d) bias += Ed[d] * bc[d * 64 + o];
    float acc[32];
#pragma unroll
    for (int bb = 0; bb < 32; ++bb) acc[bb] = bias;
    __syncthreads();

    const float* wbase = Wc + o;
    for (int ki = 0; ki < KI; ++ki) {
        float w = 0.f;
#pragma unroll
        for (int d = 0; d < DE; ++d) w += Ed[d] * wbase[(size_t)(d * KI + ki) * 64];
        const float* row = &inp[ki][bh * 32];
#pragma unroll
        for (int bq = 0; bq < 8; ++bq) {
            float4 v = *(const float4*)&row[bq * 4];
            acc[bq * 4 + 0] += v.x * w;
            acc[bq * 4 + 1] += v.y * w;
            acc[bq * 4 + 2] += v.z * w;
            acc[bq * 4 + 3] += v.w * w;
        }
    }

    float* hrow = H + (size_t)n * NCOLS + dir * 4096;
    const float* zrow = Z + ((size_t)(dir * N_NODES + n)) * 4096;
#pragma unroll
    for (int bb = 0; bb < 32; ++bb) {
        int b = bh * 32 + bb;
        float hc = tanhf(acc[bb]);
        float hp = hrow[b * 64 + o];
        float zv = zrow[b * 64 + o];
        float hn = zv * hp + (1.f - zv) * hc;
        hrow[b * 64 + o] = hn;
        HBt[(size_t)(dir * 4096 + b * 64 + o) * KPAD + n] = (f16)hn;
        out[(((size_t)b * T_STEPS + t) * N_NODES + n) * 128 + dir * 64 + o] = hn;
    }
}

// ---------------------------------------------------------------------------
extern "C" void kernel_launch(void* const* d_in, const int* in_sizes, int n_in,
                              void* d_out, int out_size, void* d_ws, size_t ws_size,
                              hipStream_t stream) {
    const float* x    = (const float*)d_in[0];
    const float* adj  = (const float*)d_in[1];
    const float* E    = (const float*)d_in[2];
    const float* Wg_f = (const float*)d_in[3];
    const float* bg_f = (const float*)d_in[4];
    const float* Wc_f = (const float*)d_in[5];
    const float* bc_f = (const float*)d_in[6];
    const float* Wg_b = (const float*)d_in[7];
    const float* bg_b = (const float*)d_in[8];
    const float* Wc_b = (const float*)d_in[9];
    const float* bc_b = (const float*)d_in[10];
    float* out = (float*)d_out;

    size_t off = 0;
    auto alloc = [&](size_t bytes) {
        void* p = (char*)d_ws + off;
        off += (bytes + 255) & ~(size_t)255;
        return p;
    };
    f16*   Sh   = (f16*)alloc((size_t)KPAD * KPAD * 2);
    f16*   XTt  = (f16*)alloc((size_t)XCOLS * KPAD * 2);
    float* SX   = (float*)alloc((size_t)N_NODES * XCOLS * 4);
    float* H    = (float*)alloc((size_t)N_NODES * NCOLS * 4);
    float* SH   = (float*)alloc((size_t)N_NODES * NCOLS * 4);
    float* RH   = (float*)alloc((size_t)N_NODES * NCOLS * 4);
    float* Z    = (float*)alloc((size_t)N_NODES * NCOLS * 4);
    f16*   HBt  = (f16*)alloc((size_t)NCOLS * KPAD * 2);
    f16*   RHBt = (f16*)alloc((size_t)NCOLS * KPAD * 2);

    hipMemsetAsync(Sh, 0, (size_t)KPAD * KPAD * 2, stream);
    hipMemsetAsync(XTt, 0, (size_t)XCOLS * KPAD * 2, stream);
    hipMemsetAsync(H, 0, (size_t)N_NODES * NCOLS * 4, stream);
    hipMemsetAsync(HBt, 0, (size_t)NCOLS * KPAD * 2, stream);
    hipMemsetAsync(RHBt, 0, (size_t)NCOLS * KPAD * 2, stream);

    k_computeS<<<N_NODES, 256, 0, stream>>>(E, adj, Sh);
    {
        int total = XCOLS * N_NODES;
        k_buildXT<<<(total + 255) / 256, 256, 0, stream>>>(x, XTt);
    }
    k_gemm_f16<<<dim3(XCOLS / 128, 7), 256, 0, stream>>>(Sh, XTt, SX, XCOLS);

    dim3 gmain(NCOLS / 128, 7);
    dim3 gapply(N_NODES, 2);
    for (int t = 0; t < T_STEPS; ++t) {
        k_gemm_f16<<<gmain, 256, 0, stream>>>(Sh, HBt, SH, NCOLS);
        k_apply_gate<<<gapply, 128, 0, stream>>>(x, E, Wg_f, bg_f, Wg_b, bg_b,
                                                 SX, SH, H, RH, RHBt, Z, t);
        k_gemm_f16<<<gmain, 256, 0, stream>>>(Sh, RHBt, SH, NCOLS);
        k_apply_cand<<<gapply, 128, 0, stream>>>(x, E, Wc_f, bc_f, Wc_b, bc_b,
                                                 SX, SH, RH, Z, H, HBt, out, t);
    }
}

// Round 4
// 3633.861 us; speedup vs baseline: 4.3251x; 1.4437x over previous
//
#include <hip/hip_runtime.h>
#include <math.h>

#define N_NODES 883
#define KPAD 896
#define T_STEPS 12
#define DE 10
#define KI 132          // CHEB_K * (DIN + DOUT) = 2 * 66
#define NCOLS 8192      // 2 dirs * 64 batch * 64 hidden
#define XCOLS 1536      // T * B * DIN
#define WSTR 160        // weight row stride (k padded 132 -> 160, zero-filled)
#define ASTR 168        // LDS inp row stride (fp16 elems): 84 words -> <=2-way on A reads

typedef _Float16 f16;
typedef __attribute__((ext_vector_type(2))) _Float16 f16x2;
typedef __attribute__((ext_vector_type(8))) _Float16 f16x8;
typedef __attribute__((ext_vector_type(4))) float f32x4;

__device__ inline void gload16(const void* g, void* l) {
    __builtin_amdgcn_global_load_lds(
        (const __attribute__((address_space(1))) unsigned int*)g,
        (__attribute__((address_space(3))) unsigned int*)l, 16, 0, 0);
}

// ---------------------------------------------------------------------------
// Sh[n][m] (fp16, padded to 896x896) = softmax(relu(E E^T), axis=1) + adj
// ---------------------------------------------------------------------------
__global__ __launch_bounds__(256) void k_computeS(const float* __restrict__ E,
                                                  const float* __restrict__ adj,
                                                  f16* __restrict__ Sh) {
    int n = blockIdx.x;
    int tid = threadIdx.x;
    __shared__ float l[N_NODES];
    __shared__ float red[8];
    float En[DE];
#pragma unroll
    for (int d = 0; d < DE; ++d) En[d] = E[n * DE + d];

    float lmax = -1e30f;
    for (int m = tid; m < N_NODES; m += 256) {
        float dot = 0.f;
#pragma unroll
        for (int d = 0; d < DE; ++d) dot += En[d] * E[m * DE + d];
        dot = fmaxf(dot, 0.f);
        l[m] = dot;
        lmax = fmaxf(lmax, dot);
    }
    int wave = tid >> 6, lane = tid & 63;
    for (int off = 32; off > 0; off >>= 1) lmax = fmaxf(lmax, __shfl_down(lmax, off));
    if (lane == 0) red[wave] = lmax;
    __syncthreads();
    float gmax = fmaxf(fmaxf(red[0], red[1]), fmaxf(red[2], red[3]));
    __syncthreads();

    float lsum = 0.f;
    for (int m = tid; m < N_NODES; m += 256) {
        float e = expf(l[m] - gmax);
        l[m] = e;
        lsum += e;
    }
    for (int off = 32; off > 0; off >>= 1) lsum += __shfl_down(lsum, off);
    if (lane == 0) red[wave] = lsum;
    __syncthreads();
    float inv = 1.0f / (red[0] + red[1] + red[2] + red[3]);
    for (int m = tid; m < N_NODES; m += 256) {
        Sh[(size_t)n * KPAD + m] = (f16)(l[m] * inv + adj[(size_t)n * N_NODES + m]);
    }
}

// ---------------------------------------------------------------------------
// XTt[c][m] (fp16, [1536][896]) = x[b,t,m,i] with c=(t*64+b)*2+i
// ---------------------------------------------------------------------------
__global__ void k_buildXT(const float* __restrict__ x, f16* __restrict__ XTt) {
    int idx = blockIdx.x * blockDim.x + threadIdx.x;
    if (idx >= XCOLS * N_NODES) return;
    int m = idx % N_NODES;
    int c = idx / N_NODES;
    int t = c >> 7;
    int b = (c >> 1) & 63;
    int i = c & 1;
    XTt[(size_t)c * KPAD + m] = (f16)x[(((size_t)b * T_STEPS + t) * N_NODES + m) * 2 + i];
}

// ---------------------------------------------------------------------------
// Per-node fp16 weights, k-contiguous, padded to WSTR with zeros.
// WgT[((dir*883+n)*128 + o)*WSTR + k], WcT[((dir*883+n)*64 + o)*WSTR + k]
// k = kc*66 + i maps to W[d][kc][i][o].
// ---------------------------------------------------------------------------
__global__ __launch_bounds__(256) void k_buildW(
    const float* __restrict__ E,
    const float* __restrict__ Wg_f, const float* __restrict__ Wg_b,
    const float* __restrict__ Wc_f, const float* __restrict__ Wc_b,
    f16* __restrict__ WgT, f16* __restrict__ WcT) {
    int n = blockIdx.x, dir = blockIdx.y;
    int tid = threadIdx.x;
    const float* Wg = dir ? Wg_b : Wg_f;
    const float* Wc = dir ? Wc_b : Wc_f;
    float Ed[DE];
#pragma unroll
    for (int d = 0; d < DE; ++d) Ed[d] = E[n * DE + d];

    f16* gdst = WgT + (size_t)(dir * N_NODES + n) * 128 * WSTR;
    {
        int o = tid & 127, seg = tid >> 7;   // 2 segs x 80 k
        for (int k = seg * 80; k < seg * 80 + 80; ++k) {
            float v = 0.f;
            if (k < KI) {
                int kc = k / 66, i = k % 66;
#pragma unroll
                for (int d = 0; d < DE; ++d)
                    v += Ed[d] * Wg[(((size_t)d * 2 + kc) * 66 + i) * 128 + o];
            }
            gdst[(size_t)o * WSTR + k] = (f16)v;
        }
    }
    f16* cdst = WcT + (size_t)(dir * N_NODES + n) * 64 * WSTR;
    {
        int o = tid & 63, seg = tid >> 6;    // 4 segs x 40 k
        for (int k = seg * 40; k < seg * 40 + 40; ++k) {
            float v = 0.f;
            if (k < KI) {
                int kc = k / 66, i = k % 66;
#pragma unroll
                for (int d = 0; d < DE; ++d)
                    v += Ed[d] * Wc[(((size_t)d * 2 + kc) * 66 + i) * 64 + o];
            }
            cdst[(size_t)o * WSTR + k] = (f16)v;
        }
    }
}

__global__ __launch_bounds__(128) void k_buildBias(
    const float* __restrict__ E,
    const float* __restrict__ bg_f, const float* __restrict__ bg_b,
    const float* __restrict__ bc_f, const float* __restrict__ bc_b,
    float* __restrict__ bgn, float* __restrict__ bcn) {
    int n = blockIdx.x, dir = blockIdx.y;
    int o = threadIdx.x;
    const float* bg = dir ? bg_b : bg_f;
    const float* bc = dir ? bc_b : bc_f;
    float Ed[DE];
#pragma unroll
    for (int d = 0; d < DE; ++d) Ed[d] = E[n * DE + d];
    float v = 0.f;
#pragma unroll
    for (int d = 0; d < DE; ++d) v += Ed[d] * bg[d * 128 + o];
    bgn[(size_t)(dir * N_NODES + n) * 128 + o] = v;
    if (o < 64) {
        float c = 0.f;
#pragma unroll
        for (int d = 0; d < DE; ++d) c += Ed[d] * bc[d * 64 + o];
        bcn[(size_t)(dir * N_NODES + n) * 64 + o] = c;
    }
}

// ---------------------------------------------------------------------------
// C[r][c] (fp16) = sum_k A[r][k] * Bt[c][k]; A [KPAD][KPAD] f16, Bt [NC][KPAD] f16
// ---------------------------------------------------------------------------
__global__ __launch_bounds__(256) void k_gemm_f16(const f16* __restrict__ A,
                                                  const f16* __restrict__ Bt,
                                                  f16* __restrict__ C, int NC) {
    __shared__ f16 Als[128 * 32];
    __shared__ f16 Bls[128 * 32];
    int tid = threadIdx.x;
    int w = tid >> 6, l = tid & 63;
    int wr = w >> 1, wc = w & 1;
    int row0 = blockIdx.y * 128;
    int col0 = blockIdx.x * 128;
    int rr = l >> 2;
    int cc = (l & 3) * 8;
    int lr = l & 15, lg = l >> 4;

    const f16* a0 = A + (size_t)(row0 + w * 32 + rr) * KPAD + cc;
    const f16* a1 = a0 + (size_t)16 * KPAD;
    const f16* b0 = Bt + (size_t)(col0 + w * 32 + rr) * KPAD + cc;
    const f16* b1 = b0 + (size_t)16 * KPAD;
    f16* la0 = &Als[(w * 32) * 32];
    f16* la1 = &Als[(w * 32 + 16) * 32];
    f16* lb0 = &Bls[(w * 32) * 32];
    f16* lb1 = &Bls[(w * 32 + 16) * 32];

    f32x4 acc[4][4];
#pragma unroll
    for (int m = 0; m < 4; ++m)
#pragma unroll
        for (int n = 0; n < 4; ++n) acc[m][n] = (f32x4)(0.f);

    for (int kt = 0; kt < KPAD / 32; ++kt) {
        int k0 = kt * 32;
        gload16(a0 + k0, la0);
        gload16(a1 + k0, la1);
        gload16(b0 + k0, lb0);
        gload16(b1 + k0, lb1);
        __syncthreads();
        f16x8 af[4], bf[4];
#pragma unroll
        for (int m = 0; m < 4; ++m)
            af[m] = *(const f16x8*)&Als[(wr * 64 + m * 16 + lr) * 32 + lg * 8];
#pragma unroll
        for (int n = 0; n < 4; ++n)
            bf[n] = *(const f16x8*)&Bls[(wc * 64 + n * 16 + lr) * 32 + lg * 8];
#pragma unroll
        for (int m = 0; m < 4; ++m)
#pragma unroll
            for (int n = 0; n < 4; ++n)
                acc[m][n] = __builtin_amdgcn_mfma_f32_16x16x32_f16(af[m], bf[n], acc[m][n], 0, 0, 0);
        __syncthreads();
    }

#pragma unroll
    for (int m = 0; m < 4; ++m) {
        int gr0 = row0 + wr * 64 + m * 16 + lg * 4;
#pragma unroll
        for (int n = 0; n < 4; ++n) {
            int gc = col0 + wc * 64 + n * 16 + lr;
            f32x4 v = acc[m][n];
#pragma unroll
            for (int q = 0; q < 4; ++q) {
                int r = gr0 + q;
                if (r < N_NODES) C[(size_t)r * NC + gc] = (f16)v[q];
            }
        }
    }
}

// ---------------------------------------------------------------------------
// Gate apply (MFMA): per (n,dir), C[64 b][128 o] = inp[64][160] x WgT[n][128][160]
// inp k: [x0,x1, h0..63, Sx0,Sx1, Sh0..63, 0-pad]
// waves 0,1 -> z (o<64) to Zh; waves 2,3 -> r -> RHh, RHBt.
// ---------------------------------------------------------------------------
__global__ __launch_bounds__(256) void k_apply_gate(
    const float* __restrict__ x, const float* __restrict__ H,
    const f16* __restrict__ SXh, const f16* __restrict__ SHh,
    const f16* __restrict__ WgT, const float* __restrict__ bgn,
    f16* __restrict__ Zh, f16* __restrict__ RHh, f16* __restrict__ RHBt, int t) {
    int n = blockIdx.x, dir = blockIdx.y;
    int tid = threadIdx.x;
    int tt = dir ? (T_STEPS - 1 - t) : t;
    __shared__ f16 inpA[64 * ASTR];

    const float* hrow = H + (size_t)n * NCOLS + dir * 4096;
    const f16* shrow = SHh + (size_t)n * NCOLS + dir * 4096;

    // h (fp32 -> fp16), k = 2..65
#pragma unroll
    for (int it = 0; it < 4; ++it) {
        int i4 = tid + it * 256;
        int b = i4 >> 4, j0 = (i4 & 15) * 4;
        float4 v = *(const float4*)&hrow[b * 64 + j0];
        f16x2 p0 = {(f16)v.x, (f16)v.y};
        f16x2 p1 = {(f16)v.z, (f16)v.w};
        *(f16x2*)&inpA[b * ASTR + 2 + j0] = p0;
        *(f16x2*)&inpA[b * ASTR + 4 + j0] = p1;
    }
    // Sh (fp16 copy), k = 68..131
#pragma unroll
    for (int it = 0; it < 8; ++it) {
        int i2 = tid + it * 256;
        int b = i2 >> 5, jp = i2 & 31;
        *(unsigned*)&inpA[b * ASTR + 68 + 2 * jp] = *(const unsigned*)&shrow[b * 64 + 2 * jp];
    }
    // x, Sx: k = 0,1 and 66,67
    if (tid < 128) {
        int b = tid >> 1, i = tid & 1;
        inpA[b * ASTR + i] = (f16)x[(((size_t)b * T_STEPS + tt) * N_NODES + n) * 2 + i];
        inpA[b * ASTR + 66 + i] = SXh[(size_t)n * XCOLS + tt * 128 + b * 2 + i];
    }
    // zero pad k = 132..159
    for (int idx = tid; idx < 64 * 14; idx += 256) {
        int b = idx / 14, p = idx % 14;
        *(unsigned*)&inpA[b * ASTR + 132 + 2 * p] = 0u;
    }
    __syncthreads();

    int w = tid >> 6, l = tid & 63;
    int lr = l & 15, lg = l >> 4;
    int o0 = w * 32;
    const f16* wbase = WgT + (size_t)(dir * N_NODES + n) * 128 * WSTR;

    f32x4 acc[4][2];
#pragma unroll
    for (int m = 0; m < 4; ++m)
#pragma unroll
        for (int j = 0; j < 2; ++j) acc[m][j] = (f32x4)(0.f);

#pragma unroll
    for (int kt = 0; kt < 5; ++kt) {
        int k0 = kt * 32 + lg * 8;
        f16x8 af[4], bf[2];
#pragma unroll
        for (int m = 0; m < 4; ++m)
            af[m] = *(const f16x8*)&inpA[(m * 16 + lr) * ASTR + k0];
#pragma unroll
        for (int j = 0; j < 2; ++j)
            bf[j] = *(const f16x8*)&wbase[(size_t)(o0 + j * 16 + lr) * WSTR + k0];
#pragma unroll
        for (int m = 0; m < 4; ++m)
#pragma unroll
            for (int j = 0; j < 2; ++j)
                acc[m][j] = __builtin_amdgcn_mfma_f32_16x16x32_f16(af[m], bf[j], acc[m][j], 0, 0, 0);
    }

    const float* bias = bgn + (size_t)(dir * N_NODES + n) * 128;
    f16* zrow = Zh + (size_t)(dir * N_NODES + n) * 4096;
    f16* rhrow = RHh + (size_t)n * NCOLS + dir * 4096;
#pragma unroll
    for (int j = 0; j < 2; ++j) {
        int o = o0 + j * 16 + lr;
        float bo = bias[o];
        if (o < 64) {
#pragma unroll
            for (int m = 0; m < 4; ++m) {
                int b0 = m * 16 + lg * 4;
                f32x4 v = acc[m][j];
#pragma unroll
                for (int q = 0; q < 4; ++q)
                    zrow[(b0 + q) * 64 + o] = (f16)(1.f / (1.f + expf(-(v[q] + bo))));
            }
        } else {
            int jj = o - 64;
#pragma unroll
            for (int m = 0; m < 4; ++m) {
                int b0 = m * 16 + lg * 4;
                f32x4 v = acc[m][j];
#pragma unroll
                for (int q = 0; q < 4; ++q) {
                    float r = 1.f / (1.f + expf(-(v[q] + bo)));
                    float rh = r * hrow[(b0 + q) * 64 + jj];
                    rhrow[(b0 + q) * 64 + jj] = (f16)rh;
                    RHBt[(size_t)(dir * 4096 + (b0 + q) * 64 + jj) * KPAD + n] = (f16)rh;
                }
            }
        }
    }
}

// ---------------------------------------------------------------------------
// Candidate apply (MFMA): per (n,dir), C[64 b][64 o]; wave w owns rows w*16..+15.
// inp k: [x0,x1, rh0..63, Sx0,Sx1, Srh0..63, 0-pad]
// ---------------------------------------------------------------------------
__global__ __launch_bounds__(256) void k_apply_cand(
    const float* __restrict__ x, const f16* __restrict__ SXh,
    const f16* __restrict__ SRHh, const f16* __restrict__ RHh,
    const f16* __restrict__ WcT, const float* __restrict__ bcn,
    const f16* __restrict__ Zh, float* __restrict__ H,
    f16* __restrict__ HBt, float* __restrict__ out, int t) {
    int n = blockIdx.x, dir = blockIdx.y;
    int tid = threadIdx.x;
    int tt = dir ? (T_STEPS - 1 - t) : t;
    __shared__ f16 inpA[64 * ASTR];

    const f16* rhrow = RHh + (size_t)n * NCOLS + dir * 4096;
    const f16* srhrow = SRHh + (size_t)n * NCOLS + dir * 4096;

#pragma unroll
    for (int it = 0; it < 8; ++it) {
        int i2 = tid + it * 256;
        int b = i2 >> 5, jp = i2 & 31;
        *(unsigned*)&inpA[b * ASTR + 2 + 2 * jp] = *(const unsigned*)&rhrow[b * 64 + 2 * jp];
        *(unsigned*)&inpA[b * ASTR + 68 + 2 * jp] = *(const unsigned*)&srhrow[b * 64 + 2 * jp];
    }
    if (tid < 128) {
        int b = tid >> 1, i = tid & 1;
        inpA[b * ASTR + i] = (f16)x[(((size_t)b * T_STEPS + tt) * N_NODES + n) * 2 + i];
        inpA[b * ASTR + 66 + i] = SXh[(size_t)n * XCOLS + tt * 128 + b * 2 + i];
    }
    for (int idx = tid; idx < 64 * 14; idx += 256) {
        int b = idx / 14, p = idx % 14;
        *(unsigned*)&inpA[b * ASTR + 132 + 2 * p] = 0u;
    }
    __syncthreads();

    int w = tid >> 6, l = tid & 63;
    int lr = l & 15, lg = l >> 4;
    const f16* wbase = WcT + (size_t)(dir * N_NODES + n) * 64 * WSTR;

    f32x4 acc[4];
#pragma unroll
    for (int j = 0; j < 4; ++j) acc[j] = (f32x4)(0.f);

#pragma unroll
    for (int kt = 0; kt < 5; ++kt) {
        int k0 = kt * 32 + lg * 8;
        f16x8 af = *(const f16x8*)&inpA[(w * 16 + lr) * ASTR + k0];
        f16x8 bf[4];
#pragma unroll
        for (int j = 0; j < 4; ++j)
            bf[j] = *(const f16x8*)&wbase[(size_t)(j * 16 + lr) * WSTR + k0];
#pragma unroll
        for (int j = 0; j < 4; ++j)
            acc[j] = __builtin_amdgcn_mfma_f32_16x16x32_f16(af, bf[j], acc[j], 0, 0, 0);
    }

    const float* bias = bcn + (size_t)(dir * N_NODES + n) * 64;
    const f16* zrow = Zh + (size_t)(dir * N_NODES + n) * 4096;
    float* hrow = H + (size_t)n * NCOLS + dir * 4096;
#pragma unroll
    for (int j = 0; j < 4; ++j) {
        int o = j * 16 + lr;
        float bo = bias[o];
        f32x4 v = acc[j];
#pragma unroll
        for (int q = 0; q < 4; ++q) {
            int b = w * 16 + lg * 4 + q;
            float hc = tanhf(v[q] + bo);
            float zv = (float)zrow[b * 64 + o];
            float hp = hrow[b * 64 + o];
            float hn = zv * hp + (1.f - zv) * hc;
            hrow[b * 64 + o] = hn;
            HBt[(size_t)(dir * 4096 + b * 64 + o) * KPAD + n] = (f16)hn;
            out[(((size_t)b * T_STEPS + t) * N_NODES + n) * 128 + dir * 64 + o] = hn;
        }
    }
}

// ---------------------------------------------------------------------------
extern "C" void kernel_launch(void* const* d_in, const int* in_sizes, int n_in,
                              void* d_out, int out_size, void* d_ws, size_t ws_size,
                              hipStream_t stream) {
    const float* x    = (const float*)d_in[0];
    const float* adj  = (const float*)d_in[1];
    const float* E    = (const float*)d_in[2];
    const float* Wg_f = (const float*)d_in[3];
    const float* bg_f = (const float*)d_in[4];
    const float* Wc_f = (const float*)d_in[5];
    const float* bc_f = (const float*)d_in[6];
    const float* Wg_b = (const float*)d_in[7];
    const float* bg_b = (const float*)d_in[8];
    const float* Wc_b = (const float*)d_in[9];
    const float* bc_b = (const float*)d_in[10];
    float* out = (float*)d_out;

    size_t off = 0;
    auto alloc = [&](size_t bytes) {
        void* p = (char*)d_ws + off;
        off += (bytes + 255) & ~(size_t)255;
        return p;
    };
    f16*   Sh   = (f16*)alloc((size_t)KPAD * KPAD * 2);
    f16*   XTt  = (f16*)alloc((size_t)XCOLS * KPAD * 2);
    f16*   SXh  = (f16*)alloc((size_t)N_NODES * XCOLS * 2);
    float* H    = (float*)alloc((size_t)N_NODES * NCOLS * 4);
    f16*   SHh  = (f16*)alloc((size_t)N_NODES * NCOLS * 2);
    f16*   RHh  = (f16*)alloc((size_t)N_NODES * NCOLS * 2);
    f16*   Zh   = (f16*)alloc((size_t)N_NODES * NCOLS * 2);
    f16*   HBt  = (f16*)alloc((size_t)NCOLS * KPAD * 2);
    f16*   RHBt = (f16*)alloc((size_t)NCOLS * KPAD * 2);
    f16*   WgT  = (f16*)alloc((size_t)2 * N_NODES * 128 * WSTR * 2);
    f16*   WcT  = (f16*)alloc((size_t)2 * N_NODES * 64 * WSTR * 2);
    float* bgn  = (float*)alloc((size_t)2 * N_NODES * 128 * 4);
    float* bcn  = (float*)alloc((size_t)2 * N_NODES * 64 * 4);

    hipMemsetAsync(Sh, 0, (size_t)KPAD * KPAD * 2, stream);
    hipMemsetAsync(XTt, 0, (size_t)XCOLS * KPAD * 2, stream);
    hipMemsetAsync(H, 0, (size_t)N_NODES * NCOLS * 4, stream);
    hipMemsetAsync(HBt, 0, (size_t)NCOLS * KPAD * 2, stream);
    hipMemsetAsync(RHBt, 0, (size_t)NCOLS * KPAD * 2, stream);

    k_computeS<<<N_NODES, 256, 0, stream>>>(E, adj, Sh);
    {
        int total = XCOLS * N_NODES;
        k_buildXT<<<(total + 255) / 256, 256, 0, stream>>>(x, XTt);
    }
    dim3 gnode(N_NODES, 2);
    k_buildW<<<gnode, 256, 0, stream>>>(E, Wg_f, Wg_b, Wc_f, Wc_b, WgT, WcT);
    k_buildBias<<<gnode, 128, 0, stream>>>(E, bg_f, bg_b, bc_f, bc_b, bgn, bcn);
    k_gemm_f16<<<dim3(XCOLS / 128, 7), 256, 0, stream>>>(Sh, XTt, SXh, XCOLS);

    dim3 gmain(NCOLS / 128, 7);
    for (int t = 0; t < T_STEPS; ++t) {
        k_gemm_f16<<<gmain, 256, 0, stream>>>(Sh, HBt, SHh, NCOLS);
        k_apply_gate<<<gnode, 256, 0, stream>>>(x, H, SXh, SHh, WgT, bgn,
                                                Zh, RHh, RHBt, t);
        k_gemm_f16<<<gmain, 256, 0, stream>>>(Sh, RHBt, SHh, NCOLS);
        k_apply_cand<<<gnode, 256, 0, stream>>>(x, SXh, SHh, RHh, WcT, bcn,
                                                Zh, H, HBt, out, t);
    }
}

// Round 5
// 2709.448 us; speedup vs baseline: 5.8007x; 1.3412x over previous
//
#include <hip/hip_runtime.h>
#include <math.h>

#define N_NODES 883
#define KPAD 896
#define T_STEPS 12
#define DE 10
#define KI 132          // CHEB_K * (DIN + DOUT) = 2 * 66
#define NCOLS 8192      // 2 dirs * 64 batch * 64 hidden
#define XCOLS 1536      // T * B * DIN
#define WSTR 160        // weight row stride (k padded 132 -> 160, zero-filled)
#define ASTR 168        // LDS inp row stride (fp16 elems)

typedef _Float16 f16;
typedef __attribute__((ext_vector_type(2))) _Float16 f16x2;
typedef __attribute__((ext_vector_type(4))) _Float16 f16x4;
typedef __attribute__((ext_vector_type(8))) _Float16 f16x8;
typedef __attribute__((ext_vector_type(4))) float f32x4;

__device__ inline void gload16(const void* g, void* l) {
    __builtin_amdgcn_global_load_lds(
        (const __attribute__((address_space(1))) unsigned int*)g,
        (__attribute__((address_space(3))) unsigned int*)l, 16, 0, 0);
}

// ---------------------------------------------------------------------------
// Sh[n][m] (fp16, padded to 896x896) = softmax(relu(E E^T), axis=1) + adj
// ---------------------------------------------------------------------------
__global__ __launch_bounds__(256) void k_computeS(const float* __restrict__ E,
                                                  const float* __restrict__ adj,
                                                  f16* __restrict__ Sh) {
    int n = blockIdx.x;
    int tid = threadIdx.x;
    __shared__ float l[N_NODES];
    __shared__ float red[8];
    float En[DE];
#pragma unroll
    for (int d = 0; d < DE; ++d) En[d] = E[n * DE + d];

    float lmax = -1e30f;
    for (int m = tid; m < N_NODES; m += 256) {
        float dot = 0.f;
#pragma unroll
        for (int d = 0; d < DE; ++d) dot += En[d] * E[m * DE + d];
        dot = fmaxf(dot, 0.f);
        l[m] = dot;
        lmax = fmaxf(lmax, dot);
    }
    int wave = tid >> 6, lane = tid & 63;
    for (int off = 32; off > 0; off >>= 1) lmax = fmaxf(lmax, __shfl_down(lmax, off));
    if (lane == 0) red[wave] = lmax;
    __syncthreads();
    float gmax = fmaxf(fmaxf(red[0], red[1]), fmaxf(red[2], red[3]));
    __syncthreads();

    float lsum = 0.f;
    for (int m = tid; m < N_NODES; m += 256) {
        float e = expf(l[m] - gmax);
        l[m] = e;
        lsum += e;
    }
    for (int off = 32; off > 0; off >>= 1) lsum += __shfl_down(lsum, off);
    if (lane == 0) red[wave] = lsum;
    __syncthreads();
    float inv = 1.0f / (red[0] + red[1] + red[2] + red[3]);
    for (int m = tid; m < N_NODES; m += 256) {
        Sh[(size_t)n * KPAD + m] = (f16)(l[m] * inv + adj[(size_t)n * N_NODES + m]);
    }
}

// ---------------------------------------------------------------------------
// XTt[c][m] (fp16, [1536][896]) = x[b,t,m,i] with c=(t*64+b)*2+i
// ---------------------------------------------------------------------------
__global__ void k_buildXT(const float* __restrict__ x, f16* __restrict__ XTt) {
    int idx = blockIdx.x * blockDim.x + threadIdx.x;
    if (idx >= XCOLS * N_NODES) return;
    int m = idx % N_NODES;
    int c = idx / N_NODES;
    int t = c >> 7;
    int b = (c >> 1) & 63;
    int i = c & 1;
    XTt[(size_t)c * KPAD + m] = (f16)x[(((size_t)b * T_STEPS + t) * N_NODES + m) * 2 + i];
}

// ---------------------------------------------------------------------------
// Per-node fp16 weights, k-contiguous, padded to WSTR with zeros.
// Coalesced: consecutive threads write consecutive flat offsets (f16x4 each).
// ---------------------------------------------------------------------------
__global__ __launch_bounds__(256) void k_buildW(
    const float* __restrict__ E,
    const float* __restrict__ Wg_f, const float* __restrict__ Wg_b,
    const float* __restrict__ Wc_f, const float* __restrict__ Wc_b,
    f16* __restrict__ WgT, f16* __restrict__ WcT) {
    int n = blockIdx.x, dir = blockIdx.y;
    int tid = threadIdx.x;
    const float* Wg = dir ? Wg_b : Wg_f;
    const float* Wc = dir ? Wc_b : Wc_f;
    float Ed[DE];
#pragma unroll
    for (int d = 0; d < DE; ++d) Ed[d] = E[n * DE + d];

    f16* gdst = WgT + (size_t)(dir * N_NODES + n) * 128 * WSTR;
#pragma unroll
    for (int it = 0; it < 20; ++it) {           // 128*160/4/256
        int f = (tid + it * 256) * 4;
        int o = f / WSTR;
        int k = f % WSTR;
        f16x4 v4;
#pragma unroll
        for (int j = 0; j < 4; ++j) {
            int kk = k + j;
            float v = 0.f;
            if (kk < KI) {
                int kc = kk / 66, i = kk % 66;
#pragma unroll
                for (int d = 0; d < DE; ++d)
                    v += Ed[d] * Wg[(((size_t)d * 2 + kc) * 66 + i) * 128 + o];
            }
            v4[j] = (f16)v;
        }
        *(f16x4*)&gdst[f] = v4;
    }

    f16* cdst = WcT + (size_t)(dir * N_NODES + n) * 64 * WSTR;
#pragma unroll
    for (int it = 0; it < 10; ++it) {           // 64*160/4/256
        int f = (tid + it * 256) * 4;
        int o = f / WSTR;
        int k = f % WSTR;
        f16x4 v4;
#pragma unroll
        for (int j = 0; j < 4; ++j) {
            int kk = k + j;
            float v = 0.f;
            if (kk < KI) {
                int kc = kk / 66, i = kk % 66;
#pragma unroll
                for (int d = 0; d < DE; ++d)
                    v += Ed[d] * Wc[(((size_t)d * 2 + kc) * 66 + i) * 64 + o];
            }
            v4[j] = (f16)v;
        }
        *(f16x4*)&cdst[f] = v4;
    }
}

__global__ __launch_bounds__(128) void k_buildBias(
    const float* __restrict__ E,
    const float* __restrict__ bg_f, const float* __restrict__ bg_b,
    const float* __restrict__ bc_f, const float* __restrict__ bc_b,
    float* __restrict__ bgn, float* __restrict__ bcn) {
    int n = blockIdx.x, dir = blockIdx.y;
    int o = threadIdx.x;
    const float* bg = dir ? bg_b : bg_f;
    const float* bc = dir ? bc_b : bc_f;
    float Ed[DE];
#pragma unroll
    for (int d = 0; d < DE; ++d) Ed[d] = E[n * DE + d];
    float v = 0.f;
#pragma unroll
    for (int d = 0; d < DE; ++d) v += Ed[d] * bg[d * 128 + o];
    bgn[(size_t)(dir * N_NODES + n) * 128 + o] = v;
    if (o < 64) {
        float c = 0.f;
#pragma unroll
        for (int d = 0; d < DE; ++d) c += Ed[d] * bc[d * 64 + o];
        bcn[(size_t)(dir * N_NODES + n) * 64 + o] = c;
    }
}

// ---------------------------------------------------------------------------
// VT[c][n'] (f16 [NCOLS][KPAD]) = V[n][c] (f16 [N_NODES][NCOLS]); zero-pads n'.
// LDS-tiled 64x64, both sides coalesced.
// ---------------------------------------------------------------------------
__global__ __launch_bounds__(256) void k_transpose(const f16* __restrict__ V,
                                                   f16* __restrict__ VT) {
    __shared__ f16 tile[64][66];
    int c0 = blockIdx.x * 64;
    int n0 = blockIdx.y * 64;
    int tid = threadIdx.x;
#pragma unroll
    for (int it = 0; it < 2; ++it) {
        int chunk = tid + it * 256;
        int r = chunk >> 3, g = chunk & 7;
        int n = n0 + r;
        f16 tmp[8];
        if (n < N_NODES) {
            f16x8 v = *(const f16x8*)&V[(size_t)n * NCOLS + c0 + g * 8];
#pragma unroll
            for (int j = 0; j < 8; ++j) tmp[j] = v[j];
        } else {
#pragma unroll
            for (int j = 0; j < 8; ++j) tmp[j] = (f16)0.f;
        }
#pragma unroll
        for (int j = 0; j < 8; ++j) tile[g * 8 + j][r] = tmp[j];
    }
    __syncthreads();
#pragma unroll
    for (int it = 0; it < 2; ++it) {
        int chunk = tid + it * 256;
        int cc = chunk >> 3, m = chunk & 7;
        f16x8 v;
#pragma unroll
        for (int j = 0; j < 8; ++j) v[j] = tile[cc][m * 8 + j];
        *(f16x8*)&VT[(size_t)(c0 + cc) * KPAD + n0 + m * 8] = v;
    }
}

// ---------------------------------------------------------------------------
// C[r][c] (fp16) = sum_k A[r][k] * Bt[c][k]; A [KPAD][KPAD] f16, Bt [NC][KPAD] f16
// ---------------------------------------------------------------------------
__global__ __launch_bounds__(256) void k_gemm_f16(const f16* __restrict__ A,
                                                  const f16* __restrict__ Bt,
                                                  f16* __restrict__ C, int NC) {
    __shared__ f16 Als[128 * 32];
    __shared__ f16 Bls[128 * 32];
    int tid = threadIdx.x;
    int w = tid >> 6, l = tid & 63;
    int wr = w >> 1, wc = w & 1;
    int row0 = blockIdx.y * 128;
    int col0 = blockIdx.x * 128;
    int rr = l >> 2;
    int cc = (l & 3) * 8;
    int lr = l & 15, lg = l >> 4;

    const f16* a0 = A + (size_t)(row0 + w * 32 + rr) * KPAD + cc;
    const f16* a1 = a0 + (size_t)16 * KPAD;
    const f16* b0 = Bt + (size_t)(col0 + w * 32 + rr) * KPAD + cc;
    const f16* b1 = b0 + (size_t)16 * KPAD;
    f16* la0 = &Als[(w * 32) * 32];
    f16* la1 = &Als[(w * 32 + 16) * 32];
    f16* lb0 = &Bls[(w * 32) * 32];
    f16* lb1 = &Bls[(w * 32 + 16) * 32];

    f32x4 acc[4][4];
#pragma unroll
    for (int m = 0; m < 4; ++m)
#pragma unroll
        for (int n = 0; n < 4; ++n) acc[m][n] = (f32x4)(0.f);

    for (int kt = 0; kt < KPAD / 32; ++kt) {
        int k0 = kt * 32;
        gload16(a0 + k0, la0);
        gload16(a1 + k0, la1);
        gload16(b0 + k0, lb0);
        gload16(b1 + k0, lb1);
        __syncthreads();
        f16x8 af[4], bf[4];
#pragma unroll
        for (int m = 0; m < 4; ++m)
            af[m] = *(const f16x8*)&Als[(wr * 64 + m * 16 + lr) * 32 + lg * 8];
#pragma unroll
        for (int n = 0; n < 4; ++n)
            bf[n] = *(const f16x8*)&Bls[(wc * 64 + n * 16 + lr) * 32 + lg * 8];
#pragma unroll
        for (int m = 0; m < 4; ++m)
#pragma unroll
            for (int n = 0; n < 4; ++n)
                acc[m][n] = __builtin_amdgcn_mfma_f32_16x16x32_f16(af[m], bf[n], acc[m][n], 0, 0, 0);
        __syncthreads();
    }

#pragma unroll
    for (int m = 0; m < 4; ++m) {
        int gr0 = row0 + wr * 64 + m * 16 + lg * 4;
#pragma unroll
        for (int n = 0; n < 4; ++n) {
            int gc = col0 + wc * 64 + n * 16 + lr;
            f32x4 v = acc[m][n];
#pragma unroll
            for (int q = 0; q < 4; ++q) {
                int r = gr0 + q;
                if (r < N_NODES) C[(size_t)r * NC + gc] = (f16)v[q];
            }
        }
    }
}

// ---------------------------------------------------------------------------
// Gate apply (MFMA): per (n,dir), C[64 b][128 o] = inp[64][160] x WgT[n][128][160]
// Row-major coalesced outputs only (Zh, RHh).
// ---------------------------------------------------------------------------
__global__ __launch_bounds__(256) void k_apply_gate(
    const float* __restrict__ x, const float* __restrict__ H,
    const f16* __restrict__ SXh, const f16* __restrict__ SHh,
    const f16* __restrict__ WgT, const float* __restrict__ bgn,
    f16* __restrict__ Zh, f16* __restrict__ RHh, int t) {
    int n = blockIdx.x, dir = blockIdx.y;
    int tid = threadIdx.x;
    int tt = dir ? (T_STEPS - 1 - t) : t;
    __shared__ f16 inpA[64 * ASTR];

    const float* hrow = H + (size_t)n * NCOLS + dir * 4096;
    const f16* shrow = SHh + (size_t)n * NCOLS + dir * 4096;

#pragma unroll
    for (int it = 0; it < 4; ++it) {
        int i4 = tid + it * 256;
        int b = i4 >> 4, j0 = (i4 & 15) * 4;
        float4 v = *(const float4*)&hrow[b * 64 + j0];
        f16x2 p0 = {(f16)v.x, (f16)v.y};
        f16x2 p1 = {(f16)v.z, (f16)v.w};
        *(f16x2*)&inpA[b * ASTR + 2 + j0] = p0;
        *(f16x2*)&inpA[b * ASTR + 4 + j0] = p1;
    }
#pragma unroll
    for (int it = 0; it < 8; ++it) {
        int i2 = tid + it * 256;
        int b = i2 >> 5, jp = i2 & 31;
        *(unsigned*)&inpA[b * ASTR + 68 + 2 * jp] = *(const unsigned*)&shrow[b * 64 + 2 * jp];
    }
    if (tid < 128) {
        int b = tid >> 1, i = tid & 1;
        inpA[b * ASTR + i] = (f16)x[(((size_t)b * T_STEPS + tt) * N_NODES + n) * 2 + i];
        inpA[b * ASTR + 66 + i] = SXh[(size_t)n * XCOLS + tt * 128 + b * 2 + i];
    }
    for (int idx = tid; idx < 64 * 14; idx += 256) {
        int b = idx / 14, p = idx % 14;
        *(unsigned*)&inpA[b * ASTR + 132 + 2 * p] = 0u;
    }
    __syncthreads();

    int w = tid >> 6, l = tid & 63;
    int lr = l & 15, lg = l >> 4;
    int o0 = w * 32;
    const f16* wbase = WgT + (size_t)(dir * N_NODES + n) * 128 * WSTR;

    f32x4 acc[4][2];
#pragma unroll
    for (int m = 0; m < 4; ++m)
#pragma unroll
        for (int j = 0; j < 2; ++j) acc[m][j] = (f32x4)(0.f);

#pragma unroll
    for (int kt = 0; kt < 5; ++kt) {
        int k0 = kt * 32 + lg * 8;
        f16x8 af[4], bf[2];
#pragma unroll
        for (int m = 0; m < 4; ++m)
            af[m] = *(const f16x8*)&inpA[(m * 16 + lr) * ASTR + k0];
#pragma unroll
        for (int j = 0; j < 2; ++j)
            bf[j] = *(const f16x8*)&wbase[(size_t)(o0 + j * 16 + lr) * WSTR + k0];
#pragma unroll
        for (int m = 0; m < 4; ++m)
#pragma unroll
            for (int j = 0; j < 2; ++j)
                acc[m][j] = __builtin_amdgcn_mfma_f32_16x16x32_f16(af[m], bf[j], acc[m][j], 0, 0, 0);
    }

    const float* bias = bgn + (size_t)(dir * N_NODES + n) * 128;
    f16* zrow = Zh + (size_t)(dir * N_NODES + n) * 4096;
    f16* rhrow = RHh + (size_t)n * NCOLS + dir * 4096;
#pragma unroll
    for (int j = 0; j < 2; ++j) {
        int o = o0 + j * 16 + lr;
        float bo = bias[o];
        if (o < 64) {
#pragma unroll
            for (int m = 0; m < 4; ++m) {
                int b0 = m * 16 + lg * 4;
                f32x4 v = acc[m][j];
#pragma unroll
                for (int q = 0; q < 4; ++q)
                    zrow[(b0 + q) * 64 + o] = (f16)(1.f / (1.f + expf(-(v[q] + bo))));
            }
        } else {
            int jj = o - 64;
#pragma unroll
            for (int m = 0; m < 4; ++m) {
                int b0 = m * 16 + lg * 4;
                f32x4 v = acc[m][j];
#pragma unroll
                for (int q = 0; q < 4; ++q) {
                    float r = 1.f / (1.f + expf(-(v[q] + bo)));
                    rhrow[(b0 + q) * 64 + jj] = (f16)(r * hrow[(b0 + q) * 64 + jj]);
                }
            }
        }
    }
}

// ---------------------------------------------------------------------------
// Candidate apply (MFMA): per (n,dir), C[64 b][64 o].
// Writes H (fp32), Hh (fp16 row-major), out (fp32). No transposed scatter.
// ---------------------------------------------------------------------------
__global__ __launch_bounds__(256) void k_apply_cand(
    const float* __restrict__ x, const f16* __restrict__ SXh,
    const f16* __restrict__ SRHh, const f16* __restrict__ RHh,
    const f16* __restrict__ WcT, const float* __restrict__ bcn,
    const f16* __restrict__ Zh, float* __restrict__ H,
    f16* __restrict__ Hh, float* __restrict__ out, int t) {
    int n = blockIdx.x, dir = blockIdx.y;
    int tid = threadIdx.x;
    int tt = dir ? (T_STEPS - 1 - t) : t;
    __shared__ f16 inpA[64 * ASTR];

    const f16* rhrow = RHh + (size_t)n * NCOLS + dir * 4096;
    const f16* srhrow = SRHh + (size_t)n * NCOLS + dir * 4096;

#pragma unroll
    for (int it = 0; it < 8; ++it) {
        int i2 = tid + it * 256;
        int b = i2 >> 5, jp = i2 & 31;
        *(unsigned*)&inpA[b * ASTR + 2 + 2 * jp] = *(const unsigned*)&rhrow[b * 64 + 2 * jp];
        *(unsigned*)&inpA[b * ASTR + 68 + 2 * jp] = *(const unsigned*)&srhrow[b * 64 + 2 * jp];
    }
    if (tid < 128) {
        int b = tid >> 1, i = tid & 1;
        inpA[b * ASTR + i] = (f16)x[(((size_t)b * T_STEPS + tt) * N_NODES + n) * 2 + i];
        inpA[b * ASTR + 66 + i] = SXh[(size_t)n * XCOLS + tt * 128 + b * 2 + i];
    }
    for (int idx = tid; idx < 64 * 14; idx += 256) {
        int b = idx / 14, p = idx % 14;
        *(unsigned*)&inpA[b * ASTR + 132 + 2 * p] = 0u;
    }
    __syncthreads();

    int w = tid >> 6, l = tid & 63;
    int lr = l & 15, lg = l >> 4;
    const f16* wbase = WcT + (size_t)(dir * N_NODES + n) * 64 * WSTR;

    f32x4 acc[4];
#pragma unroll
    for (int j = 0; j < 4; ++j) acc[j] = (f32x4)(0.f);

#pragma unroll
    for (int kt = 0; kt < 5; ++kt) {
        int k0 = kt * 32 + lg * 8;
        f16x8 af = *(const f16x8*)&inpA[(w * 16 + lr) * ASTR + k0];
        f16x8 bf[4];
#pragma unroll
        for (int j = 0; j < 4; ++j)
            bf[j] = *(const f16x8*)&wbase[(size_t)(j * 16 + lr) * WSTR + k0];
#pragma unroll
        for (int j = 0; j < 4; ++j)
            acc[j] = __builtin_amdgcn_mfma_f32_16x16x32_f16(af, bf[j], acc[j], 0, 0, 0);
    }

    const float* bias = bcn + (size_t)(dir * N_NODES + n) * 64;
    const f16* zrow = Zh + (size_t)(dir * N_NODES + n) * 4096;
    float* hrow = H + (size_t)n * NCOLS + dir * 4096;
    f16* hhrow = Hh + (size_t)n * NCOLS + dir * 4096;
#pragma unroll
    for (int j = 0; j < 4; ++j) {
        int o = j * 16 + lr;
        float bo = bias[o];
        f32x4 v = acc[j];
#pragma unroll
        for (int q = 0; q < 4; ++q) {
            int b = w * 16 + lg * 4 + q;
            float hc = tanhf(v[q] + bo);
            float zv = (float)zrow[b * 64 + o];
            float hp = hrow[b * 64 + o];
            float hn = zv * hp + (1.f - zv) * hc;
            hrow[b * 64 + o] = hn;
            hhrow[b * 64 + o] = (f16)hn;
            out[(((size_t)b * T_STEPS + t) * N_NODES + n) * 128 + dir * 64 + o] = hn;
        }
    }
}

// ---------------------------------------------------------------------------
extern "C" void kernel_launch(void* const* d_in, const int* in_sizes, int n_in,
                              void* d_out, int out_size, void* d_ws, size_t ws_size,
                              hipStream_t stream) {
    const float* x    = (const float*)d_in[0];
    const float* adj  = (const float*)d_in[1];
    const float* E    = (const float*)d_in[2];
    const float* Wg_f = (const float*)d_in[3];
    const float* bg_f = (const float*)d_in[4];
    const float* Wc_f = (const float*)d_in[5];
    const float* bc_f = (const float*)d_in[6];
    const float* Wg_b = (const float*)d_in[7];
    const float* bg_b = (const float*)d_in[8];
    const float* Wc_b = (const float*)d_in[9];
    const float* bc_b = (const float*)d_in[10];
    float* out = (float*)d_out;

    size_t off = 0;
    auto alloc = [&](size_t bytes) {
        void* p = (char*)d_ws + off;
        off += (bytes + 255) & ~(size_t)255;
        return p;
    };
    f16*   Sh   = (f16*)alloc((size_t)KPAD * KPAD * 2);
    f16*   XTt  = (f16*)alloc((size_t)XCOLS * KPAD * 2);
    f16*   SXh  = (f16*)alloc((size_t)N_NODES * XCOLS * 2);
    float* H    = (float*)alloc((size_t)N_NODES * NCOLS * 4);
    f16*   Hh   = (f16*)alloc((size_t)N_NODES * NCOLS * 2);
    f16*   SHh  = (f16*)alloc((size_t)N_NODES * NCOLS * 2);
    f16*   RHh  = (f16*)alloc((size_t)N_NODES * NCOLS * 2);
    f16*   Zh   = (f16*)alloc((size_t)N_NODES * NCOLS * 2);
    f16*   HBt  = (f16*)alloc((size_t)NCOLS * KPAD * 2);
    f16*   RHBt = (f16*)alloc((size_t)NCOLS * KPAD * 2);
    f16*   WgT  = (f16*)alloc((size_t)2 * N_NODES * 128 * WSTR * 2);
    f16*   WcT  = (f16*)alloc((size_t)2 * N_NODES * 64 * WSTR * 2);
    float* bgn  = (float*)alloc((size_t)2 * N_NODES * 128 * 4);
    float* bcn  = (float*)alloc((size_t)2 * N_NODES * 64 * 4);

    hipMemsetAsync(Sh, 0, (size_t)KPAD * KPAD * 2, stream);
    hipMemsetAsync(XTt, 0, (size_t)XCOLS * KPAD * 2, stream);
    hipMemsetAsync(H, 0, (size_t)N_NODES * NCOLS * 4, stream);
    hipMemsetAsync(HBt, 0, (size_t)NCOLS * KPAD * 2, stream);

    k_computeS<<<N_NODES, 256, 0, stream>>>(E, adj, Sh);
    {
        int total = XCOLS * N_NODES;
        k_buildXT<<<(total + 255) / 256, 256, 0, stream>>>(x, XTt);
    }
    dim3 gnode(N_NODES, 2);
    k_buildW<<<gnode, 256, 0, stream>>>(E, Wg_f, Wg_b, Wc_f, Wc_b, WgT, WcT);
    k_buildBias<<<gnode, 128, 0, stream>>>(E, bg_f, bg_b, bc_f, bc_b, bgn, bcn);
    k_gemm_f16<<<dim3(XCOLS / 128, 7), 256, 0, stream>>>(Sh, XTt, SXh, XCOLS);

    dim3 gmain(NCOLS / 128, 7);
    dim3 gtr(NCOLS / 64, KPAD / 64);
    for (int t = 0; t < T_STEPS; ++t) {
        k_gemm_f16<<<gmain, 256, 0, stream>>>(Sh, HBt, SHh, NCOLS);
        k_apply_gate<<<gnode, 256, 0, stream>>>(x, H, SXh, SHh, WgT, bgn,
                                                Zh, RHh, t);
        k_transpose<<<gtr, 256, 0, stream>>>(RHh, RHBt);
        k_gemm_f16<<<gmain, 256, 0, stream>>>(Sh, RHBt, SHh, NCOLS);
        k_apply_cand<<<gnode, 256, 0, stream>>>(x, SXh, SHh, RHh, WcT, bcn,
                                                Zh, H, Hh, out, t);
        k_transpose<<<gtr, 256, 0, stream>>>(Hh, HBt);
    }
}

// Round 7
// 1786.070 us; speedup vs baseline: 8.7996x; 1.5170x over previous
//
#include <hip/hip_runtime.h>
#include <math.h>

#define N_NODES 883
#define KPAD 896
#define T_STEPS 12
#define DE 10
#define KI 132          // CHEB_K * (DIN + DOUT) = 2 * 66
#define NCOLS 8192      // 2 dirs * 64 batch * 64 hidden
#define XCOLS 1536      // T * B * DIN
#define WSTR 160        // weight row stride (k padded 132 -> 160, zero-filled)
#define ASTR 168        // LDS inp row stride (fp16 elems)
#define GOSTR (128 * WSTR)   // 20480 gate weight elems per (n,dir)
#define COSTR (64 * WSTR)    // 10240 cand weight elems per (n,dir)

typedef _Float16 f16;
typedef __attribute__((ext_vector_type(2))) _Float16 f16x2;
typedef __attribute__((ext_vector_type(4))) _Float16 f16x4;
typedef __attribute__((ext_vector_type(8))) _Float16 f16x8;
typedef __attribute__((ext_vector_type(4))) float f32x4;

__device__ inline void gload16(const void* g, void* l) {
    __builtin_amdgcn_global_load_lds(
        (const __attribute__((address_space(1))) unsigned int*)g,
        (__attribute__((address_space(3))) unsigned int*)l, 16, 0, 0);
}

// ---------------------------------------------------------------------------
// Sh[n][m] (fp16, padded to 896x896) = softmax(relu(E E^T), axis=1) + adj
// ---------------------------------------------------------------------------
__global__ __launch_bounds__(256) void k_computeS(const float* __restrict__ E,
                                                  const float* __restrict__ adj,
                                                  f16* __restrict__ Sh) {
    int n = blockIdx.x;
    int tid = threadIdx.x;
    __shared__ float l[N_NODES];
    __shared__ float red[8];
    float En[DE];
#pragma unroll
    for (int d = 0; d < DE; ++d) En[d] = E[n * DE + d];

    float lmax = -1e30f;
    for (int m = tid; m < N_NODES; m += 256) {
        float dot = 0.f;
#pragma unroll
        for (int d = 0; d < DE; ++d) dot += En[d] * E[m * DE + d];
        dot = fmaxf(dot, 0.f);
        l[m] = dot;
        lmax = fmaxf(lmax, dot);
    }
    int wave = tid >> 6, lane = tid & 63;
    for (int off = 32; off > 0; off >>= 1) lmax = fmaxf(lmax, __shfl_down(lmax, off));
    if (lane == 0) red[wave] = lmax;
    __syncthreads();
    float gmax = fmaxf(fmaxf(red[0], red[1]), fmaxf(red[2], red[3]));
    __syncthreads();

    float lsum = 0.f;
    for (int m = tid; m < N_NODES; m += 256) {
        float e = expf(l[m] - gmax);
        l[m] = e;
        lsum += e;
    }
    for (int off = 32; off > 0; off >>= 1) lsum += __shfl_down(lsum, off);
    if (lane == 0) red[wave] = lsum;
    __syncthreads();
    float inv = 1.0f / (red[0] + red[1] + red[2] + red[3]);
    for (int m = tid; m < N_NODES; m += 256) {
        Sh[(size_t)n * KPAD + m] = (f16)(l[m] * inv + adj[(size_t)n * N_NODES + m]);
    }
}

// ---------------------------------------------------------------------------
// XTt[c][m] (fp16, [1536][896]) = x[b,t,m,i] with c=(t*64+b)*2+i
// ---------------------------------------------------------------------------
__global__ void k_buildXT(const float* __restrict__ x, f16* __restrict__ XTt) {
    int idx = blockIdx.x * blockDim.x + threadIdx.x;
    if (idx >= XCOLS * N_NODES) return;
    int m = idx % N_NODES;
    int c = idx / N_NODES;
    int t = c >> 7;
    int b = (c >> 1) & 63;
    int i = c & 1;
    XTt[(size_t)c * KPAD + m] = (f16)x[(((size_t)b * T_STEPS + t) * N_NODES + m) * 2 + i];
}

// ---------------------------------------------------------------------------
// Repack pooled weights into output flat order:
// Wg_r[((dir*DE + d)*128 + o)*WSTR + k] = Wg_dir[d][kc][i][o], k=kc*66+i (<132), else 0
// Wc_r analog with 64 outputs.
// ---------------------------------------------------------------------------
__global__ void k_reorgW(const float* __restrict__ Wg_f, const float* __restrict__ Wg_b,
                         const float* __restrict__ Wc_f, const float* __restrict__ Wc_b,
                         float* __restrict__ Wg_r, float* __restrict__ Wc_r) {
    const int GTOT = 2 * DE * GOSTR;   // 409600
    const int CTOT = 2 * DE * COSTR;   // 204800
    int idx = blockIdx.x * blockDim.x + threadIdx.x;
    if (idx < GTOT) {
        int k = idx % WSTR;
        int o = (idx / WSTR) & 127;
        int d = (idx / GOSTR) % DE;
        int dir = idx / (DE * GOSTR);
        const float* W = dir ? Wg_b : Wg_f;
        float v = 0.f;
        if (k < KI) {
            int kc = k / 66, i = k % 66;
            v = W[(((size_t)d * 2 + kc) * 66 + i) * 128 + o];
        }
        Wg_r[idx] = v;
    } else if (idx < GTOT + CTOT) {
        int j = idx - GTOT;
        int k = j % WSTR;
        int o = (j / WSTR) & 63;
        int d = (j / COSTR) % DE;
        int dir = j / (DE * COSTR);
        const float* W = dir ? Wc_b : Wc_f;
        float v = 0.f;
        if (k < KI) {
            int kc = k / 66, i = k % 66;
            v = W[(((size_t)d * 2 + kc) * 66 + i) * 64 + o];
        }
        Wc_r[j] = v;
    }
}

// ---------------------------------------------------------------------------
// Per-node weights from repacked pools. Block = (16-node group, dir, f-slice).
// z 0..3: gate quarter; z 4..5: cand half. All loads/stores coalesced;
// each Wg_r read is reused for 16 nodes.
// ---------------------------------------------------------------------------
__global__ __launch_bounds__(256) void k_buildW2(
    const float* __restrict__ E,
    const float* __restrict__ Wg_r, const float* __restrict__ Wc_r,
    f16* __restrict__ WgT, f16* __restrict__ WcT) {
    int grp = blockIdx.x, dir = blockIdx.y, z = blockIdx.z;
    int n0 = grp * 16;
    int tid = threadIdx.x;
    __shared__ float Es[16][DE];
    if (tid < 16 * DE) {
        int nn = tid / DE, d = tid % DE;
        int n = n0 + nn;
        Es[nn][d] = (n < N_NODES) ? E[n * DE + d] : 0.f;
    }
    __syncthreads();

    bool gate = z < 4;
    const float* src = gate ? (Wg_r + (size_t)dir * DE * GOSTR)
                            : (Wc_r + (size_t)dir * DE * COSTR);
    f16* dst = gate ? WgT : WcT;
    int ostr = gate ? GOSTR : COSTR;
    int slot0 = gate ? z * 1280 : (z - 4) * 1280;

#pragma unroll
    for (int it = 0; it < 5; ++it) {
        int f = (slot0 + it * 256 + tid) * 4;
        float4 v[DE];
#pragma unroll
        for (int d = 0; d < DE; ++d)
            v[d] = *(const float4*)&src[(size_t)d * ostr + f];
#pragma unroll
        for (int nn = 0; nn < 16; ++nn) {
            int n = n0 + nn;
            if (n >= N_NODES) break;
            float a0 = 0.f, a1 = 0.f, a2 = 0.f, a3 = 0.f;
#pragma unroll
            for (int d = 0; d < DE; ++d) {
                float e = Es[nn][d];
                a0 += e * v[d].x; a1 += e * v[d].y;
                a2 += e * v[d].z; a3 += e * v[d].w;
            }
            f16x4 r = {(f16)a0, (f16)a1, (f16)a2, (f16)a3};
            *(f16x4*)&dst[(size_t)(dir * N_NODES + n) * ostr + f] = r;
        }
    }
}

__global__ __launch_bounds__(128) void k_buildBias(
    const float* __restrict__ E,
    const float* __restrict__ bg_f, const float* __restrict__ bg_b,
    const float* __restrict__ bc_f, const float* __restrict__ bc_b,
    float* __restrict__ bgn, float* __restrict__ bcn) {
    int n = blockIdx.x, dir = blockIdx.y;
    int o = threadIdx.x;
    const float* bg = dir ? bg_b : bg_f;
    const float* bc = dir ? bc_b : bc_f;
    float Ed[DE];
#pragma unroll
    for (int d = 0; d < DE; ++d) Ed[d] = E[n * DE + d];
    float v = 0.f;
#pragma unroll
    for (int d = 0; d < DE; ++d) v += Ed[d] * bg[d * 128 + o];
    bgn[(size_t)(dir * N_NODES + n) * 128 + o] = v;
    if (o < 64) {
        float c = 0.f;
#pragma unroll
        for (int d = 0; d < DE; ++d) c += Ed[d] * bc[d * 64 + o];
        bcn[(size_t)(dir * N_NODES + n) * 64 + o] = c;
    }
}

// ---------------------------------------------------------------------------
// VT[c][n'] (f16 [NCOLS][KPAD]) = V[n][c] (f16 [N_NODES][NCOLS]); zero-pads n'.
// ---------------------------------------------------------------------------
__global__ __launch_bounds__(256) void k_transpose(const f16* __restrict__ V,
                                                   f16* __restrict__ VT) {
    __shared__ f16 tile[64][66];
    int c0 = blockIdx.x * 64;
    int n0 = blockIdx.y * 64;
    int tid = threadIdx.x;
#pragma unroll
    for (int it = 0; it < 2; ++it) {
        int chunk = tid + it * 256;
        int r = chunk >> 3, g = chunk & 7;
        int n = n0 + r;
        f16 tmp[8];
        if (n < N_NODES) {
            f16x8 v = *(const f16x8*)&V[(size_t)n * NCOLS + c0 + g * 8];
#pragma unroll
            for (int j = 0; j < 8; ++j) tmp[j] = v[j];
        } else {
#pragma unroll
            for (int j = 0; j < 8; ++j) tmp[j] = (f16)0.f;
        }
#pragma unroll
        for (int j = 0; j < 8; ++j) tile[g * 8 + j][r] = tmp[j];
    }
    __syncthreads();
#pragma unroll
    for (int it = 0; it < 2; ++it) {
        int chunk = tid + it * 256;
        int cc = chunk >> 3, m = chunk & 7;
        f16x8 v;
#pragma unroll
        for (int j = 0; j < 8; ++j) v[j] = tile[cc][m * 8 + j];
        *(f16x8*)&VT[(size_t)(c0 + cc) * KPAD + n0 + m * 8] = v;
    }
}

// ---------------------------------------------------------------------------
// C[r][c] (fp16) = sum_k A[r][k] * Bt[c][k]; A [KPAD][KPAD] f16, Bt [NC][KPAD] f16
// ---------------------------------------------------------------------------
__global__ __launch_bounds__(256) void k_gemm_f16(const f16* __restrict__ A,
                                                  const f16* __restrict__ Bt,
                                                  f16* __restrict__ C, int NC) {
    __shared__ f16 Als[128 * 32];
    __shared__ f16 Bls[128 * 32];
    int tid = threadIdx.x;
    int w = tid >> 6, l = tid & 63;
    int wr = w >> 1, wc = w & 1;
    int row0 = blockIdx.y * 128;
    int col0 = blockIdx.x * 128;
    int rr = l >> 2;
    int cc = (l & 3) * 8;
    int lr = l & 15, lg = l >> 4;

    const f16* a0 = A + (size_t)(row0 + w * 32 + rr) * KPAD + cc;
    const f16* a1 = a0 + (size_t)16 * KPAD;
    const f16* b0 = Bt + (size_t)(col0 + w * 32 + rr) * KPAD + cc;
    const f16* b1 = b0 + (size_t)16 * KPAD;
    f16* la0 = &Als[(w * 32) * 32];
    f16* la1 = &Als[(w * 32 + 16) * 32];
    f16* lb0 = &Bls[(w * 32) * 32];
    f16* lb1 = &Bls[(w * 32 + 16) * 32];

    f32x4 acc[4][4];
#pragma unroll
    for (int m = 0; m < 4; ++m)
#pragma unroll
        for (int n = 0; n < 4; ++n) acc[m][n] = (f32x4)(0.f);

    for (int kt = 0; kt < KPAD / 32; ++kt) {
        int k0 = kt * 32;
        gload16(a0 + k0, la0);
        gload16(a1 + k0, la1);
        gload16(b0 + k0, lb0);
        gload16(b1 + k0, lb1);
        __syncthreads();
        f16x8 af[4], bf[4];
#pragma unroll
        for (int m = 0; m < 4; ++m)
            af[m] = *(const f16x8*)&Als[(wr * 64 + m * 16 + lr) * 32 + lg * 8];
#pragma unroll
        for (int n = 0; n < 4; ++n)
            bf[n] = *(const f16x8*)&Bls[(wc * 64 + n * 16 + lr) * 32 + lg * 8];
#pragma unroll
        for (int m = 0; m < 4; ++m)
#pragma unroll
            for (int n = 0; n < 4; ++n)
                acc[m][n] = __builtin_amdgcn_mfma_f32_16x16x32_f16(af[m], bf[n], acc[m][n], 0, 0, 0);
        __syncthreads();
    }

#pragma unroll
    for (int m = 0; m < 4; ++m) {
        int gr0 = row0 + wr * 64 + m * 16 + lg * 4;
#pragma unroll
        for (int n = 0; n < 4; ++n) {
            int gc = col0 + wc * 64 + n * 16 + lr;
            f32x4 v = acc[m][n];
#pragma unroll
            for (int q = 0; q < 4; ++q) {
                int r = gr0 + q;
                if (r < N_NODES) C[(size_t)r * NC + gc] = (f16)v[q];
            }
        }
    }
}

// ---------------------------------------------------------------------------
// Gate apply (MFMA): per (n,dir), C[64 b][128 o] = inp[64][160] x WgT[n][128][160]
// ---------------------------------------------------------------------------
__global__ __launch_bounds__(256) void k_apply_gate(
    const float* __restrict__ x, const float* __restrict__ H,
    const f16* __restrict__ SXh, const f16* __restrict__ SHh,
    const f16* __restrict__ WgT, const float* __restrict__ bgn,
    f16* __restrict__ Zh, f16* __restrict__ RHh, int t) {
    int n = blockIdx.x, dir = blockIdx.y;
    int tid = threadIdx.x;
    int tt = dir ? (T_STEPS - 1 - t) : t;
    __shared__ f16 inpA[64 * ASTR];

    const float* hrow = H + (size_t)n * NCOLS + dir * 4096;
    const f16* shrow = SHh + (size_t)n * NCOLS + dir * 4096;

#pragma unroll
    for (int it = 0; it < 4; ++it) {
        int i4 = tid + it * 256;
        int b = i4 >> 4, j0 = (i4 & 15) * 4;
        float4 v = *(const float4*)&hrow[b * 64 + j0];
        f16x2 p0 = {(f16)v.x, (f16)v.y};
        f16x2 p1 = {(f16)v.z, (f16)v.w};
        *(f16x2*)&inpA[b * ASTR + 2 + j0] = p0;
        *(f16x2*)&inpA[b * ASTR + 4 + j0] = p1;
    }
#pragma unroll
    for (int it = 0; it < 8; ++it) {
        int i2 = tid + it * 256;
        int b = i2 >> 5, jp = i2 & 31;
        *(unsigned*)&inpA[b * ASTR + 68 + 2 * jp] = *(const unsigned*)&shrow[b * 64 + 2 * jp];
    }
    if (tid < 128) {
        int b = tid >> 1, i = tid & 1;
        inpA[b * ASTR + i] = (f16)x[(((size_t)b * T_STEPS + tt) * N_NODES + n) * 2 + i];
        inpA[b * ASTR + 66 + i] = SXh[(size_t)n * XCOLS + tt * 128 + b * 2 + i];
    }
    for (int idx = tid; idx < 64 * 14; idx += 256) {
        int b = idx / 14, p = idx % 14;
        *(unsigned*)&inpA[b * ASTR + 132 + 2 * p] = 0u;
    }
    __syncthreads();

    int w = tid >> 6, l = tid & 63;
    int lr = l & 15, lg = l >> 4;
    int o0 = w * 32;
    const f16* wbase = WgT + (size_t)(dir * N_NODES + n) * GOSTR;

    f32x4 acc[4][2];
#pragma unroll
    for (int m = 0; m < 4; ++m)
#pragma unroll
        for (int j = 0; j < 2; ++j) acc[m][j] = (f32x4)(0.f);

#pragma unroll
    for (int kt = 0; kt < 5; ++kt) {
        int k0 = kt * 32 + lg * 8;
        f16x8 af[4], bf[2];
#pragma unroll
        for (int m = 0; m < 4; ++m)
            af[m] = *(const f16x8*)&inpA[(m * 16 + lr) * ASTR + k0];
#pragma unroll
        for (int j = 0; j < 2; ++j)
            bf[j] = *(const f16x8*)&wbase[(size_t)(o0 + j * 16 + lr) * WSTR + k0];
#pragma unroll
        for (int m = 0; m < 4; ++m)
#pragma unroll
            for (int j = 0; j < 2; ++j)
                acc[m][j] = __builtin_amdgcn_mfma_f32_16x16x32_f16(af[m], bf[j], acc[m][j], 0, 0, 0);
    }

    const float* bias = bgn + (size_t)(dir * N_NODES + n) * 128;
    f16* zrow = Zh + (size_t)(dir * N_NODES + n) * 4096;
    f16* rhrow = RHh + (size_t)n * NCOLS + dir * 4096;
#pragma unroll
    for (int j = 0; j < 2; ++j) {
        int o = o0 + j * 16 + lr;
        float bo = bias[o];
        if (o < 64) {
#pragma unroll
            for (int m = 0; m < 4; ++m) {
                int b0 = m * 16 + lg * 4;
                f32x4 v = acc[m][j];
#pragma unroll
                for (int q = 0; q < 4; ++q)
                    zrow[(b0 + q) * 64 + o] = (f16)(1.f / (1.f + expf(-(v[q] + bo))));
            }
        } else {
            int jj = o - 64;
#pragma unroll
            for (int m = 0; m < 4; ++m) {
                int b0 = m * 16 + lg * 4;
                f32x4 v = acc[m][j];
#pragma unroll
                for (int q = 0; q < 4; ++q) {
                    float r = 1.f / (1.f + expf(-(v[q] + bo)));
                    rhrow[(b0 + q) * 64 + jj] = (f16)(r * hrow[(b0 + q) * 64 + jj]);
                }
            }
        }
    }
}

// ---------------------------------------------------------------------------
// Candidate apply (MFMA): per (n,dir), C[64 b][64 o].
// ---------------------------------------------------------------------------
__global__ __launch_bounds__(256) void k_apply_cand(
    const float* __restrict__ x, const f16* __restrict__ SXh,
    const f16* __restrict__ SRHh, const f16* __restrict__ RHh,
    const f16* __restrict__ WcT, const float* __restrict__ bcn,
    const f16* __restrict__ Zh, float* __restrict__ H,
    f16* __restrict__ Hh, float* __restrict__ out, int t) {
    int n = blockIdx.x, dir = blockIdx.y;
    int tid = threadIdx.x;
    int tt = dir ? (T_STEPS - 1 - t) : t;
    __shared__ f16 inpA[64 * ASTR];

    const f16* rhrow = RHh + (size_t)n * NCOLS + dir * 4096;
    const f16* srhrow = SRHh + (size_t)n * NCOLS + dir * 4096;

#pragma unroll
    for (int it = 0; it < 8; ++it) {
        int i2 = tid + it * 256;
        int b = i2 >> 5, jp = i2 & 31;
        *(unsigned*)&inpA[b * ASTR + 2 + 2 * jp] = *(const unsigned*)&rhrow[b * 64 + 2 * jp];
        *(unsigned*)&inpA[b * ASTR + 68 + 2 * jp] = *(const unsigned*)&srhrow[b * 64 + 2 * jp];
    }
    if (tid < 128) {
        int b = tid >> 1, i = tid & 1;
        inpA[b * ASTR + i] = (f16)x[(((size_t)b * T_STEPS + tt) * N_NODES + n) * 2 + i];
        inpA[b * ASTR + 66 + i] = SXh[(size_t)n * XCOLS + tt * 128 + b * 2 + i];
    }
    for (int idx = tid; idx < 64 * 14; idx += 256) {
        int b = idx / 14, p = idx % 14;
        *(unsigned*)&inpA[b * ASTR + 132 + 2 * p] = 0u;
    }
    __syncthreads();

    int w = tid >> 6, l = tid & 63;
    int lr = l & 15, lg = l >> 4;
    const f16* wbase = WcT + (size_t)(dir * N_NODES + n) * COSTR;

    f32x4 acc[4];
#pragma unroll
    for (int j = 0; j < 4; ++j) acc[j] = (f32x4)(0.f);

#pragma unroll
    for (int kt = 0; kt < 5; ++kt) {
        int k0 = kt * 32 + lg * 8;
        f16x8 af = *(const f16x8*)&inpA[(w * 16 + lr) * ASTR + k0];
        f16x8 bf[4];
#pragma unroll
        for (int j = 0; j < 4; ++j)
            bf[j] = *(const f16x8*)&wbase[(size_t)(j * 16 + lr) * WSTR + k0];
#pragma unroll
        for (int j = 0; j < 4; ++j)
            acc[j] = __builtin_amdgcn_mfma_f32_16x16x32_f16(af, bf[j], acc[j], 0, 0, 0);
    }

    const float* bias = bcn + (size_t)(dir * N_NODES + n) * 64;
    const f16* zrow = Zh + (size_t)(dir * N_NODES + n) * 4096;
    float* hrow = H + (size_t)n * NCOLS + dir * 4096;
    f16* hhrow = Hh + (size_t)n * NCOLS + dir * 4096;
#pragma unroll
    for (int j = 0; j < 4; ++j) {
        int o = j * 16 + lr;
        float bo = bias[o];
        f32x4 v = acc[j];
#pragma unroll
        for (int q = 0; q < 4; ++q) {
            int b = w * 16 + lg * 4 + q;
            float hc = tanhf(v[q] + bo);
            float zv = (float)zrow[b * 64 + o];
            float hp = hrow[b * 64 + o];
            float hn = zv * hp + (1.f - zv) * hc;
            hrow[b * 64 + o] = hn;
            hhrow[b * 64 + o] = (f16)hn;
            out[(((size_t)b * T_STEPS + t) * N_NODES + n) * 128 + dir * 64 + o] = hn;
        }
    }
}

// ---------------------------------------------------------------------------
extern "C" void kernel_launch(void* const* d_in, const int* in_sizes, int n_in,
                              void* d_out, int out_size, void* d_ws, size_t ws_size,
                              hipStream_t stream) {
    const float* x    = (const float*)d_in[0];
    const float* adj  = (const float*)d_in[1];
    const float* E    = (const float*)d_in[2];
    const float* Wg_f = (const float*)d_in[3];
    const float* bg_f = (const float*)d_in[4];
    const float* Wc_f = (const float*)d_in[5];
    const float* bc_f = (const float*)d_in[6];
    const float* Wg_b = (const float*)d_in[7];
    const float* bg_b = (const float*)d_in[8];
    const float* Wc_b = (const float*)d_in[9];
    const float* bc_b = (const float*)d_in[10];
    float* out = (float*)d_out;

    size_t off = 0;
    auto alloc = [&](size_t bytes) {
        void* p = (char*)d_ws + off;
        off += (bytes + 255) & ~(size_t)255;
        return p;
    };
    f16*   Sh   = (f16*)alloc((size_t)KPAD * KPAD * 2);
    f16*   XTt  = (f16*)alloc((size_t)XCOLS * KPAD * 2);
    f16*   SXh  = (f16*)alloc((size_t)N_NODES * XCOLS * 2);
    float* H    = (float*)alloc((size_t)N_NODES * NCOLS * 4);
    f16*   Hh   = (f16*)alloc((size_t)N_NODES * NCOLS * 2);
    f16*   SHh  = (f16*)alloc((size_t)N_NODES * NCOLS * 2);
    f16*   RHh  = (f16*)alloc((size_t)N_NODES * NCOLS * 2);
    f16*   Zh   = (f16*)alloc((size_t)N_NODES * NCOLS * 2);
    f16*   HBt  = (f16*)alloc((size_t)NCOLS * KPAD * 2);
    f16*   RHBt = (f16*)alloc((size_t)NCOLS * KPAD * 2);
    f16*   WgT  = (f16*)alloc((size_t)2 * N_NODES * GOSTR * 2);
    f16*   WcT  = (f16*)alloc((size_t)2 * N_NODES * COSTR * 2);
    float* bgn  = (float*)alloc((size_t)2 * N_NODES * 128 * 4);
    float* bcn  = (float*)alloc((size_t)2 * N_NODES * 64 * 4);
    // Overlay: Wg_r/Wc_r (2.46 MB, consumed by k_buildW2 before the time loop)
    // live inside RHBt (14.68 MB), which is first written by k_transpose at t=0
    // AFTER buildW2 has run. Keeps total workspace == round-5 footprint
    // (233,092,608 B, replay-proven) — round 6's appended allocs overflowed ws.
    float* Wg_r = (float*)RHBt;
    float* Wc_r = Wg_r + (size_t)2 * DE * GOSTR;

    hipMemsetAsync(Sh, 0, (size_t)KPAD * KPAD * 2, stream);
    hipMemsetAsync(XTt, 0, (size_t)XCOLS * KPAD * 2, stream);
    hipMemsetAsync(H, 0, (size_t)N_NODES * NCOLS * 4, stream);
    hipMemsetAsync(SHh, 0, (size_t)N_NODES * NCOLS * 2, stream);  // t=0: S@h0 = 0

    k_computeS<<<N_NODES, 256, 0, stream>>>(E, adj, Sh);
    {
        int total = XCOLS * N_NODES;
        k_buildXT<<<(total + 255) / 256, 256, 0, stream>>>(x, XTt);
    }
    {
        int total = 2 * DE * (GOSTR + COSTR);
        k_reorgW<<<(total + 255) / 256, 256, 0, stream>>>(Wg_f, Wg_b, Wc_f, Wc_b, Wg_r, Wc_r);
    }
    k_buildW2<<<dim3(56, 2, 6), 256, 0, stream>>>(E, Wg_r, Wc_r, WgT, WcT);
    dim3 gnode(N_NODES, 2);
    k_buildBias<<<gnode, 128, 0, stream>>>(E, bg_f, bg_b, bc_f, bc_b, bgn, bcn);
    k_gemm_f16<<<dim3(XCOLS / 128, 7), 256, 0, stream>>>(Sh, XTt, SXh, XCOLS);

    dim3 gmain(NCOLS / 128, 7);
    dim3 gtr(NCOLS / 64, KPAD / 64);
    for (int t = 0; t < T_STEPS; ++t) {
        if (t > 0)
            k_gemm_f16<<<gmain, 256, 0, stream>>>(Sh, HBt, SHh, NCOLS);
        k_apply_gate<<<gnode, 256, 0, stream>>>(x, H, SXh, SHh, WgT, bgn,
                                                Zh, RHh, t);
        k_transpose<<<gtr, 256, 0, stream>>>(RHh, RHBt);
        k_gemm_f16<<<gmain, 256, 0, stream>>>(Sh, RHBt, SHh, NCOLS);
        k_apply_cand<<<gnode, 256, 0, stream>>>(x, SXh, SHh, RHh, WcT, bcn,
                                                Zh, H, Hh, out, t);
        k_transpose<<<gtr, 256, 0, stream>>>(Hh, HBt);
    }
}

// Round 8
// 1573.700 us; speedup vs baseline: 9.9871x; 1.1349x over previous
//
#include <hip/hip_runtime.h>
#include <math.h>

#define N_NODES 883
#define KPAD 896
#define T_STEPS 12
#define DE 10
#define KI 132          // CHEB_K * (DIN + DOUT) = 2 * 66
#define NCOLS 8192      // 2 dirs * 64 batch * 64 hidden
#define XCOLS 1536      // T * B * DIN
#define WSTR 160        // weight row stride (k padded 132 -> 160; k=132 = bias col)
#define ASTR 168        // LDS inp row stride (fp16 elems)
#define GOSTR (128 * WSTR)   // 20480 gate weight elems per (n,dir)
#define COSTR (64 * WSTR)    // 10240 cand weight elems per (n,dir)

typedef _Float16 f16;
typedef __attribute__((ext_vector_type(2))) _Float16 f16x2;
typedef __attribute__((ext_vector_type(4))) _Float16 f16x4;
typedef __attribute__((ext_vector_type(8))) _Float16 f16x8;
typedef __attribute__((ext_vector_type(4))) float f32x4;

__device__ inline void gload16(const void* g, void* l) {
    __builtin_amdgcn_global_load_lds(
        (const __attribute__((address_space(1))) unsigned int*)g,
        (__attribute__((address_space(3))) unsigned int*)l, 16, 0, 0);
}

// ---------------------------------------------------------------------------
// Sh[n][m] (fp16, padded to 896x896) = softmax(relu(E E^T), axis=1) + adj
// ---------------------------------------------------------------------------
__global__ __launch_bounds__(256) void k_computeS(const float* __restrict__ E,
                                                  const float* __restrict__ adj,
                                                  f16* __restrict__ Sh) {
    int n = blockIdx.x;
    int tid = threadIdx.x;
    __shared__ float l[N_NODES];
    __shared__ float red[8];
    float En[DE];
#pragma unroll
    for (int d = 0; d < DE; ++d) En[d] = E[n * DE + d];

    float lmax = -1e30f;
    for (int m = tid; m < N_NODES; m += 256) {
        float dot = 0.f;
#pragma unroll
        for (int d = 0; d < DE; ++d) dot += En[d] * E[m * DE + d];
        dot = fmaxf(dot, 0.f);
        l[m] = dot;
        lmax = fmaxf(lmax, dot);
    }
    int wave = tid >> 6, lane = tid & 63;
    for (int off = 32; off > 0; off >>= 1) lmax = fmaxf(lmax, __shfl_down(lmax, off));
    if (lane == 0) red[wave] = lmax;
    __syncthreads();
    float gmax = fmaxf(fmaxf(red[0], red[1]), fmaxf(red[2], red[3]));
    __syncthreads();

    float lsum = 0.f;
    for (int m = tid; m < N_NODES; m += 256) {
        float e = expf(l[m] - gmax);
        l[m] = e;
        lsum += e;
    }
    for (int off = 32; off > 0; off >>= 1) lsum += __shfl_down(lsum, off);
    if (lane == 0) red[wave] = lsum;
    __syncthreads();
    float inv = 1.0f / (red[0] + red[1] + red[2] + red[3]);
    for (int m = tid; m < N_NODES; m += 256) {
        Sh[(size_t)n * KPAD + m] = (f16)(l[m] * inv + adj[(size_t)n * N_NODES + m]);
    }
}

// ---------------------------------------------------------------------------
// XTt[c][m] (fp16, [1536][896]) = x[b,t,m,i] with c=(t*64+b)*2+i
// ---------------------------------------------------------------------------
__global__ void k_buildXT(const float* __restrict__ x, f16* __restrict__ XTt) {
    int idx = blockIdx.x * blockDim.x + threadIdx.x;
    if (idx >= XCOLS * N_NODES) return;
    int m = idx % N_NODES;
    int c = idx / N_NODES;
    int t = c >> 7;
    int b = (c >> 1) & 63;
    int i = c & 1;
    XTt[(size_t)c * KPAD + m] = (f16)x[(((size_t)b * T_STEPS + t) * N_NODES + m) * 2 + i];
}

// ---------------------------------------------------------------------------
// Repack pooled weights into output flat order; k==KI carries the pooled BIAS
// (the applies feed inp[k=132]=1.0 so bias rides through the MFMA).
// Wg_r[((dir*DE + d)*128 + o)*WSTR + k], Wc_r analog with 64 outputs.
// ---------------------------------------------------------------------------
__global__ void k_reorgW(const float* __restrict__ Wg_f, const float* __restrict__ Wg_b,
                         const float* __restrict__ Wc_f, const float* __restrict__ Wc_b,
                         const float* __restrict__ bg_f, const float* __restrict__ bg_b,
                         const float* __restrict__ bc_f, const float* __restrict__ bc_b,
                         float* __restrict__ Wg_r, float* __restrict__ Wc_r) {
    const int GTOT = 2 * DE * GOSTR;   // 409600
    const int CTOT = 2 * DE * COSTR;   // 204800
    int idx = blockIdx.x * blockDim.x + threadIdx.x;
    if (idx < GTOT) {
        int k = idx % WSTR;
        int o = (idx / WSTR) & 127;
        int d = (idx / GOSTR) % DE;
        int dir = idx / (DE * GOSTR);
        float v = 0.f;
        if (k < KI) {
            const float* W = dir ? Wg_b : Wg_f;
            int kc = k / 66, i = k % 66;
            v = W[(((size_t)d * 2 + kc) * 66 + i) * 128 + o];
        } else if (k == KI) {
            v = (dir ? bg_b : bg_f)[d * 128 + o];
        }
        Wg_r[idx] = v;
    } else if (idx < GTOT + CTOT) {
        int j = idx - GTOT;
        int k = j % WSTR;
        int o = (j / WSTR) & 63;
        int d = (j / COSTR) % DE;
        int dir = j / (DE * COSTR);
        float v = 0.f;
        if (k < KI) {
            const float* W = dir ? Wc_b : Wc_f;
            int kc = k / 66, i = k % 66;
            v = W[(((size_t)d * 2 + kc) * 66 + i) * 64 + o];
        } else if (k == KI) {
            v = (dir ? bc_b : bc_f)[d * 64 + o];
        }
        Wc_r[j] = v;
    }
}

// ---------------------------------------------------------------------------
// Per-node weights from repacked pools. Block = (16-node group, dir, f-slice).
// z 0..3: gate quarter; z 4..5: cand half. All loads/stores coalesced;
// each Wg_r read is reused for 16 nodes. Bias column flows through unchanged.
// ---------------------------------------------------------------------------
__global__ __launch_bounds__(256) void k_buildW2(
    const float* __restrict__ E,
    const float* __restrict__ Wg_r, const float* __restrict__ Wc_r,
    f16* __restrict__ WgT, f16* __restrict__ WcT) {
    int grp = blockIdx.x, dir = blockIdx.y, z = blockIdx.z;
    int n0 = grp * 16;
    int tid = threadIdx.x;
    __shared__ float Es[16][DE];
    if (tid < 16 * DE) {
        int nn = tid / DE, d = tid % DE;
        int n = n0 + nn;
        Es[nn][d] = (n < N_NODES) ? E[n * DE + d] : 0.f;
    }
    __syncthreads();

    bool gate = z < 4;
    const float* src = gate ? (Wg_r + (size_t)dir * DE * GOSTR)
                            : (Wc_r + (size_t)dir * DE * COSTR);
    f16* dst = gate ? WgT : WcT;
    int ostr = gate ? GOSTR : COSTR;
    int slot0 = gate ? z * 1280 : (z - 4) * 1280;

#pragma unroll
    for (int it = 0; it < 5; ++it) {
        int f = (slot0 + it * 256 + tid) * 4;
        float4 v[DE];
#pragma unroll
        for (int d = 0; d < DE; ++d)
            v[d] = *(const float4*)&src[(size_t)d * ostr + f];
#pragma unroll
        for (int nn = 0; nn < 16; ++nn) {
            int n = n0 + nn;
            if (n >= N_NODES) break;
            float a0 = 0.f, a1 = 0.f, a2 = 0.f, a3 = 0.f;
#pragma unroll
            for (int d = 0; d < DE; ++d) {
                float e = Es[nn][d];
                a0 += e * v[d].x; a1 += e * v[d].y;
                a2 += e * v[d].z; a3 += e * v[d].w;
            }
            f16x4 r = {(f16)a0, (f16)a1, (f16)a2, (f16)a3};
            *(f16x4*)&dst[(size_t)(dir * N_NODES + n) * ostr + f] = r;
        }
    }
}

// ---------------------------------------------------------------------------
// VT[c][n'] (f16 [NCOLS][KPAD]) = V[n][c] (f16 [N_NODES][NCOLS]); zero-pads n'.
// ---------------------------------------------------------------------------
__global__ __launch_bounds__(256) void k_transpose(const f16* __restrict__ V,
                                                   f16* __restrict__ VT) {
    __shared__ f16 tile[64][66];
    int c0 = blockIdx.x * 64;
    int n0 = blockIdx.y * 64;
    int tid = threadIdx.x;
#pragma unroll
    for (int it = 0; it < 2; ++it) {
        int chunk = tid + it * 256;
        int r = chunk >> 3, g = chunk & 7;
        int n = n0 + r;
        f16 tmp[8];
        if (n < N_NODES) {
            f16x8 v = *(const f16x8*)&V[(size_t)n * NCOLS + c0 + g * 8];
#pragma unroll
            for (int j = 0; j < 8; ++j) tmp[j] = v[j];
        } else {
#pragma unroll
            for (int j = 0; j < 8; ++j) tmp[j] = (f16)0.f;
        }
#pragma unroll
        for (int j = 0; j < 8; ++j) tile[g * 8 + j][r] = tmp[j];
    }
    __syncthreads();
#pragma unroll
    for (int it = 0; it < 2; ++it) {
        int chunk = tid + it * 256;
        int cc = chunk >> 3, m = chunk & 7;
        f16x8 v;
#pragma unroll
        for (int j = 0; j < 8; ++j) v[j] = tile[cc][m * 8 + j];
        *(f16x8*)&VT[(size_t)(c0 + cc) * KPAD + n0 + m * 8] = v;
    }
}

// ---------------------------------------------------------------------------
// C[r][c] (fp16) = sum_k A[r][k] * Bt[c][k]; A [KPAD][KPAD] f16, Bt [NC][KPAD] f16
// ---------------------------------------------------------------------------
__global__ __launch_bounds__(256) void k_gemm_f16(const f16* __restrict__ A,
                                                  const f16* __restrict__ Bt,
                                                  f16* __restrict__ C, int NC) {
    __shared__ f16 Als[128 * 32];
    __shared__ f16 Bls[128 * 32];
    int tid = threadIdx.x;
    int w = tid >> 6, l = tid & 63;
    int wr = w >> 1, wc = w & 1;
    int row0 = blockIdx.y * 128;
    int col0 = blockIdx.x * 128;
    int rr = l >> 2;
    int cc = (l & 3) * 8;
    int lr = l & 15, lg = l >> 4;

    const f16* a0 = A + (size_t)(row0 + w * 32 + rr) * KPAD + cc;
    const f16* a1 = a0 + (size_t)16 * KPAD;
    const f16* b0 = Bt + (size_t)(col0 + w * 32 + rr) * KPAD + cc;
    const f16* b1 = b0 + (size_t)16 * KPAD;
    f16* la0 = &Als[(w * 32) * 32];
    f16* la1 = &Als[(w * 32 + 16) * 32];
    f16* lb0 = &Bls[(w * 32) * 32];
    f16* lb1 = &Bls[(w * 32 + 16) * 32];

    f32x4 acc[4][4];
#pragma unroll
    for (int m = 0; m < 4; ++m)
#pragma unroll
        for (int n = 0; n < 4; ++n) acc[m][n] = (f32x4)(0.f);

    for (int kt = 0; kt < KPAD / 32; ++kt) {
        int k0 = kt * 32;
        gload16(a0 + k0, la0);
        gload16(a1 + k0, la1);
        gload16(b0 + k0, lb0);
        gload16(b1 + k0, lb1);
        __syncthreads();
        f16x8 af[4], bf[4];
#pragma unroll
        for (int m = 0; m < 4; ++m)
            af[m] = *(const f16x8*)&Als[(wr * 64 + m * 16 + lr) * 32 + lg * 8];
#pragma unroll
        for (int n = 0; n < 4; ++n)
            bf[n] = *(const f16x8*)&Bls[(wc * 64 + n * 16 + lr) * 32 + lg * 8];
#pragma unroll
        for (int m = 0; m < 4; ++m)
#pragma unroll
            for (int n = 0; n < 4; ++n)
                acc[m][n] = __builtin_amdgcn_mfma_f32_16x16x32_f16(af[m], bf[n], acc[m][n], 0, 0, 0);
        __syncthreads();
    }

#pragma unroll
    for (int m = 0; m < 4; ++m) {
        int gr0 = row0 + wr * 64 + m * 16 + lg * 4;
#pragma unroll
        for (int n = 0; n < 4; ++n) {
            int gc = col0 + wc * 64 + n * 16 + lr;
            f32x4 v = acc[m][n];
#pragma unroll
            for (int q = 0; q < 4; ++q) {
                int r = gr0 + q;
                if (r < N_NODES) C[(size_t)r * NC + gc] = (f16)v[q];
            }
        }
    }
}

// ---------------------------------------------------------------------------
// Gate apply (MFMA): per (n,dir), C[64 b][128 o] = inp[64][160] x WgT[n][128][160]
// State h is fp16 (Hh). Bias folded into weight col k=132 (inp slot = 1.0).
// first=1 (t==0): S@h == 0, skip SHh reads.
// ---------------------------------------------------------------------------
__global__ __launch_bounds__(256) void k_apply_gate(
    const float* __restrict__ x, const f16* __restrict__ Hh,
    const f16* __restrict__ SXh, const f16* __restrict__ SHh,
    const f16* __restrict__ WgT,
    f16* __restrict__ Zh, f16* __restrict__ RHh, int t, int first) {
    int n = blockIdx.x, dir = blockIdx.y;
    int tid = threadIdx.x;
    int tt = dir ? (T_STEPS - 1 - t) : t;
    __shared__ f16 inpA[64 * ASTR];

    const f16* hhrow = Hh + (size_t)n * NCOLS + dir * 4096;
    const f16* shrow = SHh + (size_t)n * NCOLS + dir * 4096;

#pragma unroll
    for (int it = 0; it < 8; ++it) {
        int i2 = tid + it * 256;
        int b = i2 >> 5, jp = i2 & 31;
        *(unsigned*)&inpA[b * ASTR + 2 + 2 * jp] = *(const unsigned*)&hhrow[b * 64 + 2 * jp];
        *(unsigned*)&inpA[b * ASTR + 68 + 2 * jp] =
            first ? 0u : *(const unsigned*)&shrow[b * 64 + 2 * jp];
    }
    if (tid < 128) {
        int b = tid >> 1, i = tid & 1;
        inpA[b * ASTR + i] = (f16)x[(((size_t)b * T_STEPS + tt) * N_NODES + n) * 2 + i];
        inpA[b * ASTR + 66 + i] = SXh[(size_t)n * XCOLS + tt * 128 + b * 2 + i];
    }
    // pad k=132..159; k=132 carries 1.0 so the weight bias column applies
    for (int idx = tid; idx < 64 * 14; idx += 256) {
        int b = idx / 14, p = idx % 14;
        *(unsigned*)&inpA[b * ASTR + 132 + 2 * p] = (p == 0) ? 0x00003C00u : 0u;
    }
    __syncthreads();

    int w = tid >> 6, l = tid & 63;
    int lr = l & 15, lg = l >> 4;
    int o0 = w * 32;
    const f16* wbase = WgT + (size_t)(dir * N_NODES + n) * GOSTR;

    f32x4 acc[4][2];
#pragma unroll
    for (int m = 0; m < 4; ++m)
#pragma unroll
        for (int j = 0; j < 2; ++j) acc[m][j] = (f32x4)(0.f);

#pragma unroll
    for (int kt = 0; kt < 5; ++kt) {
        int k0 = kt * 32 + lg * 8;
        f16x8 af[4], bf[2];
#pragma unroll
        for (int m = 0; m < 4; ++m)
            af[m] = *(const f16x8*)&inpA[(m * 16 + lr) * ASTR + k0];
#pragma unroll
        for (int j = 0; j < 2; ++j)
            bf[j] = *(const f16x8*)&wbase[(size_t)(o0 + j * 16 + lr) * WSTR + k0];
#pragma unroll
        for (int m = 0; m < 4; ++m)
#pragma unroll
            for (int j = 0; j < 2; ++j)
                acc[m][j] = __builtin_amdgcn_mfma_f32_16x16x32_f16(af[m], bf[j], acc[m][j], 0, 0, 0);
    }

    f16* zrow = Zh + (size_t)(dir * N_NODES + n) * 4096;
    f16* rhrow = RHh + (size_t)n * NCOLS + dir * 4096;
#pragma unroll
    for (int j = 0; j < 2; ++j) {
        int o = o0 + j * 16 + lr;
        if (o < 64) {
#pragma unroll
            for (int m = 0; m < 4; ++m) {
                int b0 = m * 16 + lg * 4;
                f32x4 v = acc[m][j];
#pragma unroll
                for (int q = 0; q < 4; ++q)
                    zrow[(b0 + q) * 64 + o] = (f16)(1.f / (1.f + expf(-v[q])));
            }
        } else {
            int jj = o - 64;
#pragma unroll
            for (int m = 0; m < 4; ++m) {
                int b0 = m * 16 + lg * 4;
                f32x4 v = acc[m][j];
#pragma unroll
                for (int q = 0; q < 4; ++q) {
                    float r = 1.f / (1.f + expf(-v[q]));
                    rhrow[(b0 + q) * 64 + jj] =
                        (f16)(r * (float)hhrow[(b0 + q) * 64 + jj]);
                }
            }
        }
    }
}

// ---------------------------------------------------------------------------
// Candidate apply (MFMA): per (n,dir), C[64 b][64 o]. fp16 state update.
// ---------------------------------------------------------------------------
__global__ __launch_bounds__(256) void k_apply_cand(
    const float* __restrict__ x, const f16* __restrict__ SXh,
    const f16* __restrict__ SRHh, const f16* __restrict__ RHh,
    const f16* __restrict__ WcT, const f16* __restrict__ Zh,
    f16* __restrict__ Hh, float* __restrict__ out, int t) {
    int n = blockIdx.x, dir = blockIdx.y;
    int tid = threadIdx.x;
    int tt = dir ? (T_STEPS - 1 - t) : t;
    __shared__ f16 inpA[64 * ASTR];

    const f16* rhrow = RHh + (size_t)n * NCOLS + dir * 4096;
    const f16* srhrow = SRHh + (size_t)n * NCOLS + dir * 4096;

#pragma unroll
    for (int it = 0; it < 8; ++it) {
        int i2 = tid + it * 256;
        int b = i2 >> 5, jp = i2 & 31;
        *(unsigned*)&inpA[b * ASTR + 2 + 2 * jp] = *(const unsigned*)&rhrow[b * 64 + 2 * jp];
        *(unsigned*)&inpA[b * ASTR + 68 + 2 * jp] = *(const unsigned*)&srhrow[b * 64 + 2 * jp];
    }
    if (tid < 128) {
        int b = tid >> 1, i = tid & 1;
        inpA[b * ASTR + i] = (f16)x[(((size_t)b * T_STEPS + tt) * N_NODES + n) * 2 + i];
        inpA[b * ASTR + 66 + i] = SXh[(size_t)n * XCOLS + tt * 128 + b * 2 + i];
    }
    for (int idx = tid; idx < 64 * 14; idx += 256) {
        int b = idx / 14, p = idx % 14;
        *(unsigned*)&inpA[b * ASTR + 132 + 2 * p] = (p == 0) ? 0x00003C00u : 0u;
    }
    __syncthreads();

    int w = tid >> 6, l = tid & 63;
    int lr = l & 15, lg = l >> 4;
    const f16* wbase = WcT + (size_t)(dir * N_NODES + n) * COSTR;

    f32x4 acc[4];
#pragma unroll
    for (int j = 0; j < 4; ++j) acc[j] = (f32x4)(0.f);

#pragma unroll
    for (int kt = 0; kt < 5; ++kt) {
        int k0 = kt * 32 + lg * 8;
        f16x8 af = *(const f16x8*)&inpA[(w * 16 + lr) * ASTR + k0];
        f16x8 bf[4];
#pragma unroll
        for (int j = 0; j < 4; ++j)
            bf[j] = *(const f16x8*)&wbase[(size_t)(j * 16 + lr) * WSTR + k0];
#pragma unroll
        for (int j = 0; j < 4; ++j)
            acc[j] = __builtin_amdgcn_mfma_f32_16x16x32_f16(af, bf[j], acc[j], 0, 0, 0);
    }

    const f16* zrow = Zh + (size_t)(dir * N_NODES + n) * 4096;
    f16* hhrow = Hh + (size_t)n * NCOLS + dir * 4096;
#pragma unroll
    for (int j = 0; j < 4; ++j) {
        int o = j * 16 + lr;
        f32x4 v = acc[j];
#pragma unroll
        for (int q = 0; q < 4; ++q) {
            int b = w * 16 + lg * 4 + q;
            float hc = tanhf(v[q]);
            float zv = (float)zrow[b * 64 + o];
            float hp = (float)hhrow[b * 64 + o];
            float hn = zv * hp + (1.f - zv) * hc;
            hhrow[b * 64 + o] = (f16)hn;
            out[(((size_t)b * T_STEPS + t) * N_NODES + n) * 128 + dir * 64 + o] = hn;
        }
    }
}

// ---------------------------------------------------------------------------
extern "C" void kernel_launch(void* const* d_in, const int* in_sizes, int n_in,
                              void* d_out, int out_size, void* d_ws, size_t ws_size,
                              hipStream_t stream) {
    const float* x    = (const float*)d_in[0];
    const float* adj  = (const float*)d_in[1];
    const float* E    = (const float*)d_in[2];
    const float* Wg_f = (const float*)d_in[3];
    const float* bg_f = (const float*)d_in[4];
    const float* Wc_f = (const float*)d_in[5];
    const float* bc_f = (const float*)d_in[6];
    const float* Wg_b = (const float*)d_in[7];
    const float* bg_b = (const float*)d_in[8];
    const float* Wc_b = (const float*)d_in[9];
    const float* bc_b = (const float*)d_in[10];
    float* out = (float*)d_out;

    size_t off = 0;
    auto alloc = [&](size_t bytes) {
        void* p = (char*)d_ws + off;
        off += (bytes + 255) & ~(size_t)255;
        return p;
    };
    f16*   Sh   = (f16*)alloc((size_t)KPAD * KPAD * 2);
    f16*   XTt  = (f16*)alloc((size_t)XCOLS * KPAD * 2);
    f16*   SXh  = (f16*)alloc((size_t)N_NODES * XCOLS * 2);
    f16*   Hh   = (f16*)alloc((size_t)N_NODES * NCOLS * 2);
    f16*   SHh  = (f16*)alloc((size_t)N_NODES * NCOLS * 2);
    f16*   RHh  = (f16*)alloc((size_t)N_NODES * NCOLS * 2);
    f16*   Zh   = (f16*)alloc((size_t)N_NODES * NCOLS * 2);
    f16*   HBt  = (f16*)alloc((size_t)NCOLS * KPAD * 2);
    f16*   RHBt = (f16*)alloc((size_t)NCOLS * KPAD * 2);
    f16*   WgT  = (f16*)alloc((size_t)2 * N_NODES * GOSTR * 2);
    f16*   WcT  = (f16*)alloc((size_t)2 * N_NODES * COSTR * 2);
    // Overlay: Wg_r/Wc_r (2.46 MB, consumed by k_buildW2 before the time loop)
    // live inside RHBt (14.68 MB), which is first written by k_transpose at t=0
    // AFTER buildW2 has run. Workspace total stays below the round-5 proven
    // footprint (round 6 lesson: appended allocs overflowed ws).
    float* Wg_r = (float*)RHBt;
    float* Wc_r = Wg_r + (size_t)2 * DE * GOSTR;

    hipMemsetAsync(Sh, 0, (size_t)KPAD * KPAD * 2, stream);
    hipMemsetAsync(XTt, 0, (size_t)XCOLS * KPAD * 2, stream);
    hipMemsetAsync(Hh, 0, (size_t)N_NODES * NCOLS * 2, stream);

    k_computeS<<<N_NODES, 256, 0, stream>>>(E, adj, Sh);
    {
        int total = XCOLS * N_NODES;
        k_buildXT<<<(total + 255) / 256, 256, 0, stream>>>(x, XTt);
    }
    {
        int total = 2 * DE * (GOSTR + COSTR);
        k_reorgW<<<(total + 255) / 256, 256, 0, stream>>>(Wg_f, Wg_b, Wc_f, Wc_b,
                                                          bg_f, bg_b, bc_f, bc_b,
                                                          Wg_r, Wc_r);
    }
    k_buildW2<<<dim3(56, 2, 6), 256, 0, stream>>>(E, Wg_r, Wc_r, WgT, WcT);
    k_gemm_f16<<<dim3(XCOLS / 128, 7), 256, 0, stream>>>(Sh, XTt, SXh, XCOLS);

    dim3 gnode(N_NODES, 2);
    dim3 gmain(NCOLS / 128, 7);
    dim3 gtr(NCOLS / 64, KPAD / 64);
    for (int t = 0; t < T_STEPS; ++t) {
        if (t > 0)
            k_gemm_f16<<<gmain, 256, 0, stream>>>(Sh, HBt, SHh, NCOLS);
        k_apply_gate<<<gnode, 256, 0, stream>>>(x, Hh, SXh, SHh, WgT,
                                                Zh, RHh, t, t == 0 ? 1 : 0);
        k_transpose<<<gtr, 256, 0, stream>>>(RHh, RHBt);
        k_gemm_f16<<<gmain, 256, 0, stream>>>(Sh, RHBt, SHh, NCOLS);
        k_apply_cand<<<gnode, 256, 0, stream>>>(x, SXh, SHh, RHh, WcT,
                                                Zh, Hh, out, t);
        k_transpose<<<gtr, 256, 0, stream>>>(Hh, HBt);
    }
}